// Round 9
// baseline (7122.355 us; speedup 1.0000x reference)
//
#include <hip/hip_runtime.h>
#include <cstdint>
#include <cstddef>

typedef unsigned short ushort_t;
typedef unsigned int uint_t;

#define NATOMS 8000
#define NEDGES 100000
#define NTRIP  500000
#define NGRAPH 64
#define HD     128
#define NRR    6
#define NSNR   42
#define NBB    8
#define NBLKS  6
#define MSZ    16384

using short8   = __attribute__((ext_vector_type(8))) short;
using ushort8v = __attribute__((ext_vector_type(8))) unsigned short;
using floatx4  = __attribute__((ext_vector_type(4))) float;

__device__ __forceinline__ float siluf(float x){ return x / (1.f + __expf(-x)); }
__device__ __forceinline__ ushort_t f2us(float f){
    uint_t u = __builtin_bit_cast(uint_t, f);
    u = (u + 0x7FFFu + ((u >> 16) & 1u)) >> 16;
    return (ushort_t)u;
}
__device__ __forceinline__ float us2f(ushort_t s){
    uint_t u = ((uint_t)s) << 16;
    return __builtin_bit_cast(float, u);
}
__device__ __forceinline__ void wave_lds_fence(){
    asm volatile("s_waitcnt lgkmcnt(0)" ::: "memory");
}

__global__ void zerof_k(float* __restrict__ p, int n){ int i=blockIdx.x*256+threadIdx.x; if(i<n) p[i]=0.f; }
__global__ void zeroi_k(int* __restrict__ p, int n){ int i=blockIdx.x*256+threadIdx.x; if(i<n) p[i]=0; }

// ---------------- weight prep ----------------
__global__ __launch_bounds__(256)
void transp128_k(const float* __restrict__ src, ushort_t* __restrict__ dst)
{
    __shared__ ushort_t L[128][130];
    int m = blockIdx.x;
    const float* S = src + (size_t)m * MSZ;
    ushort_t* D = dst + (size_t)m * MSZ;
    int tid = threadIdx.x;
    #pragma unroll
    for (int p = 0; p < 64; ++p) {
        int idx = p * 256 + tid;
        int k = idx >> 7, n = idx & 127;
        L[k][n] = f2us(S[idx]);
    }
    __syncthreads();
    #pragma unroll
    for (int p = 0; p < 64; ++p) {
        int idx = p * 256 + tid;
        int n = idx >> 7, k = idx & 127;
        D[idx] = L[k][n];
    }
}

__global__ void castWM_k(const float* __restrict__ src, ushort_t* __restrict__ dst, int n)
{
    int i = blockIdx.x * 256 + threadIdx.x;
    if (i < n) dst[i] = f2us(src[i]);
}

__global__ void pack_bc_k(const float* __restrict__ bef, const float* __restrict__ lin,
                          const float* __restrict__ aft, float* __restrict__ bc)
{
    int b = blockIdx.x;
    for (int i = threadIdx.x; i < 7 * HD; i += 256) {
        int s = i >> 7, h = i & 127;
        float v;
        if (s < 2)      v = bef[(size_t)(b * 2 + s) * HD + h];
        else if (s == 2) v = lin[(size_t)b * HD + h];
        else             v = aft[(size_t)(b * 4 + (s - 3)) * HD + h];
        bc[(size_t)b * 7 * HD + i] = v;
    }
}

// ---------------- CSR build ----------------
__global__ void hist_k(const int* __restrict__ idx, int n, int* __restrict__ cnt)
{
    int i = blockIdx.x * 256 + threadIdx.x;
    if (i < n) atomicAdd(&cnt[idx[i]], 1);
}
__global__ void blksum_k(const int* __restrict__ c, int n, int* __restrict__ bs)
{
    int i = blockIdx.x * 256 + threadIdx.x;
    int v = (i < n) ? c[i] : 0;
    #pragma unroll
    for (int off = 32; off; off >>= 1) v += __shfl_down(v, off);
    __shared__ int sh[4];
    if ((threadIdx.x & 63) == 0) sh[threadIdx.x >> 6] = v;
    __syncthreads();
    if (threadIdx.x == 0) bs[blockIdx.x] = sh[0] + sh[1] + sh[2] + sh[3];
}
__global__ void scanb_k(int* __restrict__ bs, int nb)
{
    __shared__ int sh[1024];
    int t = threadIdx.x;
    int v = (t < nb) ? bs[t] : 0;
    sh[t] = v; __syncthreads();
    for (int off = 1; off < 1024; off <<= 1) {
        int u = (t >= off) ? sh[t - off] : 0;
        __syncthreads();
        sh[t] += u;
        __syncthreads();
    }
    if (t < nb) bs[t] = sh[t] - v;
}
__global__ void scanfin_k(const int* __restrict__ c, int n, const int* __restrict__ bs,
                          int* __restrict__ offs)
{
    __shared__ int sh[256];
    int t = threadIdx.x;
    int i = blockIdx.x * 256 + t;
    int v = (i < n) ? c[i] : 0;
    sh[t] = v; __syncthreads();
    for (int off = 1; off < 256; off <<= 1) {
        int u = (t >= off) ? sh[t - off] : 0;
        __syncthreads();
        sh[t] += u;
        __syncthreads();
    }
    if (i < n)  offs[i] = bs[blockIdx.x] + sh[t] - v;
    if (i == n - 1) offs[n] = bs[blockIdx.x] + sh[t];
}
__global__ void fill_k(const int* __restrict__ idx, int n, const int* __restrict__ offs,
                       int* __restrict__ cur, int* __restrict__ sorted)
{
    int i = blockIdx.x * 256 + threadIdx.x;
    if (i >= n) return;
    int e = idx[i];
    int p = offs[e] + atomicAdd(&cur[e], 1);
    sorted[p] = i;
}
// tpos[t]=k, ekjs[k]=idx_kj[tsorted[k]]
__global__ void invperm_k(const int* __restrict__ tsorted, const int* __restrict__ idx_kj,
                          int* __restrict__ tpos, int* __restrict__ ekjs, int n)
{
    int k = blockIdx.x * 256 + threadIdx.x;
    if (k >= n) return;
    int t = tsorted[k];
    tpos[t] = k;
    ekjs[k] = idx_kj[t];
}

// ---------------------------------------------------------------------------
// Legacy block helpers (emb_chain only)
// ---------------------------------------------------------------------------
__device__ __forceinline__ void load_bh(const ushort_t* Bt, int kh, int tid, ushort8v r[4])
{
    #pragma unroll
    for (int p = 0; p < 4; ++p) {
        int c = p * 256 + tid;
        int n = c >> 3, c8 = c & 7;
        r[p] = *(const ushort8v*)(Bt + (size_t)n * 128 + kh * 64 + c8 * 8);
    }
}
__device__ __forceinline__ void store_bh(ushort8v r[4], ushort_t (*Bl)[72], int tid)
{
    #pragma unroll
    for (int p = 0; p < 4; ++p) {
        int c = p * 256 + tid;
        *(ushort8v*)&Bl[c >> 3][(c & 7) * 8] = r[p];
    }
}
__device__ __forceinline__ void mfma_kh(ushort_t (*Al)[136], ushort_t (*Bl)[72],
                                        floatx4 acc[4][4], int kh,
                                        int wr, int wc, int lhi, int llo)
{
    #pragma unroll
    for (int ks = 0; ks < 2; ++ks) {
        int kk = ks * 32 + lhi * 8;
        short8 af[4], bf[4];
        #pragma unroll
        for (int tm = 0; tm < 4; ++tm)
            af[tm] = *(const short8*)&Al[wr * 64 + tm * 16 + llo][kh * 64 + kk];
        #pragma unroll
        for (int tn = 0; tn < 4; ++tn)
            bf[tn] = *(const short8*)&Bl[wc * 64 + tn * 16 + llo][kk];
        #pragma unroll
        for (int tm = 0; tm < 4; ++tm)
            #pragma unroll
            for (int tn = 0; tn < 4; ++tn)
                acc[tm][tn] = __builtin_amdgcn_mfma_f32_16x16x32_bf16(
                    af[tm], bf[tn], acc[tm][tn], 0, 0, 0);
    }
}
#define ZERO_ACC4(acc) { _Pragma("unroll") for (int a_=0;a_<4;++a_) _Pragma("unroll") \
    for (int b_=0;b_<4;++b_) _Pragma("unroll") for (int q_=0;q_<4;++q_) acc[a_][b_][q_]=0.f; }
#define ZERO_ACC8(acc) { _Pragma("unroll") for (int t_=0;t_<8;++t_) { acc[t_][0]=0.f; acc[t_][1]=0.f; acc[t_][2]=0.f; acc[t_][3]=0.f; } }

// ---------------------------------------------------------------------------
// Embedding chain (block-tiled, validated r7/r8)
// ---------------------------------------------------------------------------
__global__ __launch_bounds__(256)
void emb_chain_k(const float* __restrict__ rbf, const float* __restrict__ W6g,
                 const float* __restrict__ b6g, const ushort_t* __restrict__ Wemb3,
                 const float* __restrict__ A0, const float* __restrict__ A1,
                 const float* __restrict__ emb_b, const int* __restrict__ z,
                 const int* __restrict__ ii, const int* __restrict__ jj,
                 float* __restrict__ X, ushort_t* __restrict__ Xb, int M)
{
    __shared__ ushort_t Al[128][136];
    __shared__ ushort_t Bl[128][72];
    __shared__ float W6[NRR * HD];
    __shared__ float b6s[HD];
    const int tid = threadIdx.x, row0 = blockIdx.x * 128;
    const int wave = tid >> 6, lane = tid & 63;
    const int wr = wave >> 1, wc_ = wave & 1, lhi = lane >> 4, llo = lane & 15;

    for (int i = tid; i < NRR * HD; i += 256) W6[i] = W6g[i];
    if (tid < HD) b6s[tid] = b6g[tid];
    ushort8v r0[4], r1[4];
    load_bh(Wemb3, 0, tid, r0); load_bh(Wemb3, 1, tid, r1);
    __syncthreads();

    {
        int e_l = tid >> 1, half = tid & 1;
        int grow = row0 + e_l; if (grow >= M) grow = M - 1;
        float r6[NRR];
        #pragma unroll
        for (int r = 0; r < NRR; ++r) r6[r] = rbf[(size_t)grow * NRR + r];
        #pragma unroll 8
        for (int hh = 0; hh < 64; ++hh) {
            int h = half * 64 + hh;
            float a = b6s[h];
            #pragma unroll
            for (int r = 0; r < NRR; ++r) a += r6[r] * W6[r * HD + h];
            Al[e_l][h] = f2us(siluf(a));
        }
    }
    __syncthreads();

    floatx4 acc[4][4]; ZERO_ACC4(acc);
    store_bh(r0, Bl, tid); __syncthreads();
    mfma_kh(Al, Bl, acc, 0, wr, wc_, lhi, llo);
    __syncthreads();
    store_bh(r1, Bl, tid); __syncthreads();
    mfma_kh(Al, Bl, acc, 1, wr, wc_, lhi, llo);

    #pragma unroll
    for (int tm = 0; tm < 4; ++tm)
        #pragma unroll
        for (int q = 0; q < 4; ++q) {
            int grow = row0 + wr * 64 + tm * 16 + lhi * 4 + q;
            if (grow >= M) continue;
            int zi = z[ii[grow]], zj = z[jj[grow]];
            #pragma unroll
            for (int tn = 0; tn < 4; ++tn) {
                int coll = wc_ * 64 + tn * 16 + llo;
                float t = acc[tm][tn][q] + A0[zi * HD + coll] + A1[zj * HD + coll] + emb_b[coll];
                float v = siluf(t);
                size_t o = (size_t)grow * HD + coll;
                X[o] = v; Xb[o] = f2us(v);
            }
        }
}

// ---------------------------------------------------------------------------
// kjcb: Cb = bf16( silu(x@Wkj+b) * rbfp )  — wave-autonomous, 16 rows/wave
// ---------------------------------------------------------------------------
__global__ __launch_bounds__(256, 3)
void kjcb_w(const ushort_t* __restrict__ Xb, const ushort_t* __restrict__ Wkj,
            const float* __restrict__ bkj, const float* __restrict__ rbf,
            const float* __restrict__ Wr6, ushort_t* __restrict__ Cb, int M)
{
    __shared__ float W6s[NRR * HD];
    __shared__ float bkjS[HD];
    const int tid = threadIdx.x, wave = tid >> 6, lane = tid & 63;
    const int llo = lane & 15, lhi = lane >> 4;
    for (int i = tid; i < NRR * HD; i += 256) W6s[i] = Wr6[i];
    if (tid < HD) bkjS[tid] = bkj[tid];
    __syncthreads();
    const int row0 = (blockIdx.x * 4 + wave) * 16;
    if (row0 >= M) return;

    short8 af[4];
    #pragma unroll
    for (int kc = 0; kc < 4; ++kc)
        af[kc] = *(const short8*)(Xb + (size_t)(row0 + llo) * HD + kc * 32 + lhi * 8);

    float rb[4][NRR];
    {
        const float* rp = rbf + (size_t)(row0 + lhi * 4) * NRR;
        #pragma unroll
        for (int q = 0; q < 4; ++q)
            #pragma unroll
            for (int r = 0; r < NRR; ++r) rb[q][r] = rp[q * NRR + r];
    }

    floatx4 acc[8]; ZERO_ACC8(acc);
    #pragma unroll
    for (int kc = 0; kc < 4; ++kc) {
        short8 bq[8];
        #pragma unroll
        for (int tn = 0; tn < 8; ++tn)
            bq[tn] = *(const short8*)(Wkj + (size_t)(tn * 16 + llo) * HD + kc * 32 + lhi * 8);
        #pragma unroll
        for (int tn = 0; tn < 8; ++tn)
            acc[tn] = __builtin_amdgcn_mfma_f32_16x16x32_bf16(af[kc], bq[tn], acc[tn], 0, 0, 0);
    }
    #pragma unroll
    for (int tn = 0; tn < 8; ++tn) {
        int col = tn * 16 + llo;
        #pragma unroll
        for (int q = 0; q < 4; ++q) {
            int grow = row0 + lhi * 4 + q;
            if (grow >= M) continue;
            float rpv = 0.f;
            #pragma unroll
            for (int r = 0; r < NRR; ++r) rpv += rb[q][r] * W6s[r * HD + col];
            Cb[(size_t)grow * HD + col] = f2us(siluf(acc[tn][q] + bkjS[col]) * rpv);
        }
    }
}

// ---------------------------------------------------------------------------
// MEGATRIP: per wave 16 edge rows, end-to-end:
//   phase1: j-chunked triplet accumulation (regs) -> wave LDS -> K=256 MFMA
//           vs int_W, accumulating m into macc
//   phase2: x_ji GEMM -> hin = x_ji + m
//   phase3: 7-step mega chain (trunk in regs) -> write X fp32 + Xb bf16 once
// ---------------------------------------------------------------------------
__global__ __launch_bounds__(256, 2)
void megatrip_w(const ushort_t* __restrict__ Xb, const ushort_t* __restrict__ Cb,
                const ushort_t* __restrict__ sps, const int* __restrict__ toffs,
                const int* __restrict__ ekjs,
                const ushort_t* __restrict__ Wm,       // [128][1024]
                const ushort_t* __restrict__ Wji, const float* __restrict__ bjig,
                const ushort_t* __restrict__ Wc, const float* __restrict__ Bc,
                float* __restrict__ X, ushort_t* __restrict__ Xbo, int M)
{
    __shared__ float bjiS[HD];
    __shared__ float bs[7 * HD];
    __shared__ ushort_t T[4][16][264];   // per-wave 16 x 256 (+8 pad)
    const int tid = threadIdx.x, wave = tid >> 6, lane = tid & 63;
    const int llo = lane & 15, lhi = lane >> 4;
    if (tid < HD) bjiS[tid] = bjig[tid];
    for (int i = tid; i < 7 * HD; i += 256) bs[i] = Bc[i];
    __syncthreads();
    const int row0 = (blockIdx.x * 4 + wave) * 16;
    if (row0 >= M) return;
    ushort_t (*Tw)[264] = T[wave];

    floatx4 macc[8]; ZERO_ACC8(macc);

    // ---------- phase 1: 4 j-chunks ----------
    for (int jc = 0; jc < 4; ++jc) {
        float g[16][4];   // [el][jd*2+hd]
        #pragma unroll
        for (int el = 0; el < 16; ++el)
            #pragma unroll
            for (int v = 0; v < 4; ++v) g[el][v] = 0.f;

        for (int el = 0; el < 16; ++el) {
            int e = row0 + el;
            int k1 = toffs[e + 1];
            for (int k = toffs[e]; k < k1; ++k) {
                int ekj = ekjs[k];
                uint_t spv = *(const uint_t*)(sps + (size_t)k * NBB + jc * 2);
                float s0 = us2f((ushort_t)(spv & 0xFFFFu));
                float s1 = us2f((ushort_t)(spv >> 16));
                float c0 = us2f(Cb[(size_t)ekj * HD + lane]);
                float c1 = us2f(Cb[(size_t)ekj * HD + 64 + lane]);
                g[el][0] += s0 * c0; g[el][1] += s0 * c1;
                g[el][2] += s1 * c0; g[el][3] += s1 * c1;
            }
        }
        // repack g -> Tw[16][256]: k = jd*128 + h, h = hd*64 + lane
        #pragma unroll
        for (int el = 0; el < 16; ++el) {
            Tw[el][lane]       = f2us(g[el][0]);
            Tw[el][64 + lane]  = f2us(g[el][1]);
            Tw[el][128 + lane] = f2us(g[el][2]);
            Tw[el][192 + lane] = f2us(g[el][3]);
        }
        wave_lds_fence();
        // GEMM 16x256 @ Wm[:, jc*256 .. +256] -> macc
        #pragma unroll
        for (int kc = 0; kc < 8; ++kc) {
            short8 a8 = *(const short8*)&Tw[llo][kc * 32 + lhi * 8];
            short8 bq[8];
            #pragma unroll
            for (int tn = 0; tn < 8; ++tn)
                bq[tn] = *(const short8*)(Wm + (size_t)(tn * 16 + llo) * 1024 + jc * 256 + kc * 32 + lhi * 8);
            #pragma unroll
            for (int tn = 0; tn < 8; ++tn)
                macc[tn] = __builtin_amdgcn_mfma_f32_16x16x32_bf16(a8, bq[tn], macc[tn], 0, 0, 0);
        }
        wave_lds_fence();  // a8 reads done before next chunk's repack
    }

    // ---------- phase 2: x_ji GEMM, hin = x_ji + m ----------
    float hin[8][4];
    {
        short8 af[4];
        #pragma unroll
        for (int kc = 0; kc < 4; ++kc)
            af[kc] = *(const short8*)(Xb + (size_t)(row0 + llo) * HD + kc * 32 + lhi * 8);
        floatx4 acc[8]; ZERO_ACC8(acc);
        #pragma unroll
        for (int kc = 0; kc < 4; ++kc) {
            short8 bq[8];
            #pragma unroll
            for (int tn = 0; tn < 8; ++tn)
                bq[tn] = *(const short8*)(Wji + (size_t)(tn * 16 + llo) * HD + kc * 32 + lhi * 8);
            #pragma unroll
            for (int tn = 0; tn < 8; ++tn)
                acc[tn] = __builtin_amdgcn_mfma_f32_16x16x32_bf16(af[kc], bq[tn], acc[tn], 0, 0, 0);
        }
        #pragma unroll
        for (int tn = 0; tn < 8; ++tn) {
            int col = tn * 16 + llo;
            #pragma unroll
            for (int q = 0; q < 4; ++q)
                hin[tn][q] = siluf(acc[tn][q] + bjiS[col]) + macc[tn][q];
        }
    }

    // ---------- phase 3: mega chain ----------
    float cur[8][4], trunk[8][4];
    #pragma unroll
    for (int tn = 0; tn < 8; ++tn)
        #pragma unroll
        for (int q = 0; q < 4; ++q) cur[tn][q] = hin[tn][q];

    for (int s = 0; s < 7; ++s) {
        #pragma unroll
        for (int tn = 0; tn < 8; ++tn)
            #pragma unroll
            for (int q = 0; q < 4; ++q)
                Tw[lhi * 4 + q][tn * 16 + llo] = f2us(cur[tn][q]);
        wave_lds_fence();

        const ushort_t* W = Wc + (size_t)s * MSZ;
        floatx4 acc[8]; ZERO_ACC8(acc);
        #pragma unroll
        for (int kc = 0; kc < 4; ++kc) {
            short8 a8 = *(const short8*)&Tw[llo][kc * 32 + lhi * 8];
            short8 bq[8];
            #pragma unroll
            for (int tn = 0; tn < 8; ++tn)
                bq[tn] = *(const short8*)(W + (size_t)(tn * 16 + llo) * HD + kc * 32 + lhi * 8);
            #pragma unroll
            for (int tn = 0; tn < 8; ++tn)
                acc[tn] = __builtin_amdgcn_mfma_f32_16x16x32_bf16(a8, bq[tn], acc[tn], 0, 0, 0);
        }
        wave_lds_fence();

        #pragma unroll
        for (int tn = 0; tn < 8; ++tn) {
            int col = tn * 16 + llo;
            #pragma unroll
            for (int q = 0; q < 4; ++q) {
                int grow = row0 + lhi * 4 + q;
                float t = siluf(acc[tn][q] + bs[s * HD + col]);
                if (s == 0)      cur[tn][q] = t;
                else if (s == 1) cur[tn][q] = t + hin[tn][q];
                else if (s == 2) { cur[tn][q] = t + X[(size_t)grow * HD + col]; trunk[tn][q] = cur[tn][q]; }
                else if (s == 3 || s == 5) cur[tn][q] = t;
                else { cur[tn][q] = t + trunk[tn][q]; trunk[tn][q] = cur[tn][q]; }
            }
        }
    }
    #pragma unroll
    for (int tn = 0; tn < 8; ++tn) {
        int col = tn * 16 + llo;
        #pragma unroll
        for (int q = 0; q < 4; ++q) {
            int grow = row0 + lhi * 4 + q;
            if (grow >= M) continue;
            size_t o = (size_t)grow * HD + col;
            X[o] = cur[tn][q];
            Xbo[o] = f2us(cur[tn][q]);
        }
    }
}

// ---------------------------------------------------------------------------
// Atom-side: wide CSR gather kernel + small chain kernel
// ---------------------------------------------------------------------------
__global__ __launch_bounds__(256)
void gatherT_k(const ushort_t* __restrict__ Xb, const float* __restrict__ rbf,
               const float* __restrict__ Wr6, const int* __restrict__ eoffs,
               const int* __restrict__ esorted, ushort_t* __restrict__ TA, int M)
{
    __shared__ float W6s[NRR * HD];
    const int tid = threadIdx.x, wave = tid >> 6, lane = tid & 63;
    for (int i = tid; i < NRR * HD; i += 256) W6s[i] = Wr6[i];
    __syncthreads();
    int a0 = (blockIdx.x * 4 + wave) * 2;
    #pragma unroll
    for (int s = 0; s < 2; ++s) {
        int a = a0 + s;
        if (a >= M) return;
        float acc0 = 0.f, acc1 = 0.f;
        int k1 = eoffs[a + 1];
        for (int k = eoffs[a]; k < k1; ++k) {
            int e = esorted[k];
            float r6[NRR];
            #pragma unroll
            for (int r = 0; r < NRR; ++r) r6[r] = rbf[(size_t)e * NRR + r];
            float rp0 = 0.f, rp1 = 0.f;
            #pragma unroll
            for (int r = 0; r < NRR; ++r) {
                rp0 += r6[r] * W6s[r * HD + lane];
                rp1 += r6[r] * W6s[r * HD + 64 + lane];
            }
            acc0 += rp0 * us2f(Xb[(size_t)e * HD + lane]);
            acc1 += rp1 * us2f(Xb[(size_t)e * HD + 64 + lane]);
        }
        TA[(size_t)a * HD + lane] = f2us(acc0);
        TA[(size_t)a * HD + 64 + lane] = f2us(acc1);
    }
}

__global__ __launch_bounds__(256, 3)
void atomchain_w(const ushort_t* __restrict__ TA, const ushort_t* __restrict__ Wl,
                 const float* __restrict__ bl, const float* __restrict__ wout,
                 float* __restrict__ P, int M)
{
    __shared__ float blS[3 * HD];
    __shared__ float woS[HD];
    __shared__ ushort_t T[4][16][136];
    const int tid = threadIdx.x, wave = tid >> 6, lane = tid & 63;
    const int llo = lane & 15, lhi = lane >> 4;
    for (int i = tid; i < 3 * HD; i += 256) blS[i] = bl[i];
    if (tid < HD) woS[tid] = wout[tid];
    __syncthreads();
    const int row0 = (blockIdx.x * 4 + wave) * 16;
    if (row0 >= M) return;
    ushort_t (*Tw)[136] = T[wave];

    #pragma unroll
    for (int s = 0; s < 3; ++s) {
        short8 af[4];
        if (s == 0) {
            #pragma unroll
            for (int kc = 0; kc < 4; ++kc)
                af[kc] = *(const short8*)(TA + (size_t)(row0 + llo) * HD + kc * 32 + lhi * 8);
        } else {
            #pragma unroll
            for (int kc = 0; kc < 4; ++kc)
                af[kc] = *(const short8*)&Tw[llo][kc * 32 + lhi * 8];
        }
        const ushort_t* W = Wl + (size_t)s * MSZ;
        floatx4 acc[8]; ZERO_ACC8(acc);
        #pragma unroll
        for (int kc = 0; kc < 4; ++kc) {
            short8 bq[8];
            #pragma unroll
            for (int tn = 0; tn < 8; ++tn)
                bq[tn] = *(const short8*)(W + (size_t)(tn * 16 + llo) * HD + kc * 32 + lhi * 8);
            #pragma unroll
            for (int tn = 0; tn < 8; ++tn)
                acc[tn] = __builtin_amdgcn_mfma_f32_16x16x32_bf16(af[kc], bq[tn], acc[tn], 0, 0, 0);
        }
        if (s < 2) {
            wave_lds_fence();  // prior af reads done (s>=1)
            #pragma unroll
            for (int tn = 0; tn < 8; ++tn) {
                int col = tn * 16 + llo;
                #pragma unroll
                for (int q = 0; q < 4; ++q)
                    Tw[lhi * 4 + q][col] = f2us(siluf(acc[tn][q] + blS[s * HD + col]));
            }
            wave_lds_fence();
        } else {
            #pragma unroll
            for (int q = 0; q < 4; ++q) {
                float v = 0.f;
                #pragma unroll
                for (int tn = 0; tn < 8; ++tn) {
                    int col = tn * 16 + llo;
                    v += siluf(acc[tn][q] + blS[2 * HD + col]) * woS[col];
                }
                v += __shfl_xor(v, 1); v += __shfl_xor(v, 2);
                v += __shfl_xor(v, 4); v += __shfl_xor(v, 8);
                int a = row0 + lhi * 4 + q;
                if (llo == 0 && a < M) P[a] += v;
            }
        }
    }
}

// ---------------- small kernels ----------------
__global__ void emb_lin_k(const float* __restrict__ emb_table, const float* __restrict__ emb_w,
                          float* __restrict__ A0, float* __restrict__ A1)
{
    __shared__ float er[HD];
    int a = blockIdx.x, h = threadIdx.x;
    er[h] = emb_table[a * HD + h];
    __syncthreads();
    float acc0 = 0.f, acc1 = 0.f;
    #pragma unroll 8
    for (int l = 0; l < HD; ++l) {
        float e = er[l];
        acc0 += e * emb_w[l * HD + h];
        acc1 += e * emb_w[(HD + l) * HD + h];
    }
    A0[a * HD + h] = acc0;
    A1[a * HD + h] = acc1;
}

// sbf projection, written directly in tsorted order via tpos
__global__ void sbf_proj_s(const float* __restrict__ sbf, const float* __restrict__ W,
                           const int* __restrict__ tpos, ushort_t* __restrict__ sps)
{
    __shared__ float Ws[NSNR * NBB];
    for (int s = threadIdx.x; s < NSNR * NBB; s += 256) Ws[s] = W[s];
    __syncthreads();
    int t = blockIdx.x * 256 + threadIdx.x;
    if (t >= NTRIP) return;
    float acc[NBB];
    #pragma unroll
    for (int n = 0; n < NBB; ++n) acc[n] = 0.f;
    #pragma unroll
    for (int r = 0; r < NSNR; ++r) {
        float v = sbf[(size_t)t * NSNR + r];
        #pragma unroll
        for (int n = 0; n < NBB; ++n) acc[n] += v * Ws[r * NBB + n];
    }
    int p = tpos[t];
    ushort_t* o = sps + (size_t)p * NBB;
    #pragma unroll
    for (int n = 0; n < NBB; ++n) o[n] = f2us(acc[n]);
}

__global__ void graph_sum_k(const float* __restrict__ P, const int* __restrict__ batch,
                            float* __restrict__ outg)
{
    int a = blockIdx.x * 256 + threadIdx.x;
    if (a >= NATOMS) return;
    atomicAdd(&outg[batch[a]], P[a]);
}

// ---------------------------------------------------------------------------
extern "C" void kernel_launch(void* const* d_in, const int* in_sizes, int n_in,
                              void* d_out, int out_size, void* d_ws, size_t ws_size,
                              hipStream_t stream)
{
    const int*   z         = (const int*)  d_in[0];
    const float* rbf       = (const float*)d_in[1];
    const float* sbf       = (const float*)d_in[2];
    const int*   ii        = (const int*)  d_in[3];
    const int*   jj        = (const int*)  d_in[4];
    const int*   idx_kj    = (const int*)  d_in[5];
    const int*   idx_ji    = (const int*)  d_in[6];
    const int*   batch     = (const int*)  d_in[7];
    const float* emb_table = (const float*)d_in[8];
    const float* emb_rbf_w = (const float*)d_in[9];
    const float* emb_rbf_b = (const float*)d_in[10];
    const float* emb_w     = (const float*)d_in[11];
    const float* emb_b     = (const float*)d_in[12];
    const float* int_rbf_w = (const float*)d_in[13];
    const float* int_sbf_w = (const float*)d_in[14];
    const float* int_kj_w  = (const float*)d_in[15];
    const float* int_kj_b  = (const float*)d_in[16];
    const float* int_ji_w  = (const float*)d_in[17];
    const float* int_ji_b  = (const float*)d_in[18];
    const float* int_W     = (const float*)d_in[19];
    const float* int_bef_w = (const float*)d_in[20];
    const float* int_bef_b = (const float*)d_in[21];
    const float* int_lin_w = (const float*)d_in[22];
    const float* int_lin_b = (const float*)d_in[23];
    const float* int_aft_w = (const float*)d_in[24];
    const float* int_aft_b = (const float*)d_in[25];
    const float* out_rbf_w = (const float*)d_in[26];
    const float* out_lins_w= (const float*)d_in[27];
    const float* out_lins_b= (const float*)d_in[28];
    const float* out_w     = (const float*)d_in[29];
    float* d_outf          = (float*)d_out;

    const size_t EH = (size_t)NEDGES * HD;
    const int OFF_EMB = 0, OFF_KJ = 1, OFF_JI = 7, OFF_CHAIN = 13, OFF_OUTL = 55;

    char* base = (char*)d_ws;
    auto take = [&](size_t bytes) { char* p = base; base += (bytes + 255) & ~(size_t)255; return p; };
    float* bufA    = (float*)take(EH * 4);                     // X fp32 trunk
    ushort_t* Xb   = (ushort_t*)take(EH * 2);                  // X bf16 shadow
    ushort_t* Cb   = (ushort_t*)take(EH * 2);                  // x_kj bf16
    ushort_t* sps  = (ushort_t*)take((size_t)NTRIP * NBB * 2); // sp in tsorted order
    ushort_t* TA   = (ushort_t*)take((size_t)NATOMS * HD * 2); // atom gather out (bf16)
    float* P_atom  = (float*)take((size_t)NATOMS * 4);
    float* A0      = (float*)take(95 * HD * 4);
    float* A1      = (float*)take(95 * HD * 4);
    float* bc      = (float*)take((size_t)NBLKS * 7 * HD * 4);
    int*   counts  = (int*)  take((size_t)(NEDGES + 1) * 4);
    int*   bsum    = (int*)  take(1024 * 4);
    int*   toffs   = (int*)  take((size_t)(NEDGES + 1) * 4);
    int*   eoffs   = (int*)  take((size_t)(NATOMS + 1) * 4);
    int*   tsorted = (int*)  take((size_t)NTRIP * 4);
    int*   esorted = (int*)  take((size_t)NEDGES * 4);
    int*   tpos    = (int*)  take((size_t)NTRIP * 4);
    int*   ekjs    = (int*)  take((size_t)NTRIP * 4);
    ushort_t* w128 = (ushort_t*)take((size_t)76 * MSZ * 2);
    ushort_t* wM   = (ushort_t*)take((size_t)NBLKS * HD * 1024 * 2);

    auto zero = [&](float* p, size_t n) {
        zerof_k<<<((int)n + 255) / 256, 256, 0, stream>>>(p, (int)n);
    };

    // ---------------- weight prep ----------------
    transp128_k<<< 1, 256, 0, stream>>>(emb_w + 2 * MSZ, w128 + (size_t)OFF_EMB * MSZ);
    transp128_k<<< 6, 256, 0, stream>>>(int_kj_w,   w128 + (size_t)OFF_KJ  * MSZ);
    transp128_k<<< 6, 256, 0, stream>>>(int_ji_w,   w128 + (size_t)OFF_JI  * MSZ);
    for (int b = 0; b < NBLKS; ++b) {
        transp128_k<<<2, 256, 0, stream>>>(int_bef_w + (size_t)b * 2 * MSZ,
                                           w128 + (size_t)(OFF_CHAIN + b * 7) * MSZ);
        transp128_k<<<1, 256, 0, stream>>>(int_lin_w + (size_t)b * MSZ,
                                           w128 + (size_t)(OFF_CHAIN + b * 7 + 2) * MSZ);
        transp128_k<<<4, 256, 0, stream>>>(int_aft_w + (size_t)b * 4 * MSZ,
                                           w128 + (size_t)(OFF_CHAIN + b * 7 + 3) * MSZ);
    }
    transp128_k<<<21, 256, 0, stream>>>(out_lins_w, w128 + (size_t)OFF_OUTL * MSZ);
    castWM_k<<<(NBLKS * HD * 1024 + 255) / 256, 256, 0, stream>>>(int_W, wM, NBLKS * HD * 1024);
    pack_bc_k<<<NBLKS, 256, 0, stream>>>(int_bef_b, int_lin_b, int_aft_b, bc);

    // ---------------- CSR builds ----------------
    {
        zeroi_k<<<(NEDGES + 255) / 256, 256, 0, stream>>>(counts, NEDGES);
        hist_k<<<(NTRIP + 255) / 256, 256, 0, stream>>>(idx_ji, NTRIP, counts);
        int nb = (NEDGES + 255) / 256;
        blksum_k<<<nb, 256, 0, stream>>>(counts, NEDGES, bsum);
        scanb_k<<<1, 1024, 0, stream>>>(bsum, nb);
        scanfin_k<<<nb, 256, 0, stream>>>(counts, NEDGES, bsum, toffs);
        zeroi_k<<<(NEDGES + 255) / 256, 256, 0, stream>>>(counts, NEDGES);
        fill_k<<<(NTRIP + 255) / 256, 256, 0, stream>>>(idx_ji, NTRIP, toffs, counts, tsorted);
        invperm_k<<<(NTRIP + 255) / 256, 256, 0, stream>>>(tsorted, idx_kj, tpos, ekjs, NTRIP);
    }
    {
        zeroi_k<<<(NATOMS + 255) / 256, 256, 0, stream>>>(counts, NATOMS);
        hist_k<<<(NEDGES + 255) / 256, 256, 0, stream>>>(ii, NEDGES, counts);
        int nb = (NATOMS + 255) / 256;
        blksum_k<<<nb, 256, 0, stream>>>(counts, NATOMS, bsum);
        scanb_k<<<1, 1024, 0, stream>>>(bsum, nb);
        scanfin_k<<<nb, 256, 0, stream>>>(counts, NATOMS, bsum, eoffs);
        zeroi_k<<<(NATOMS + 255) / 256, 256, 0, stream>>>(counts, NATOMS);
        fill_k<<<(NEDGES + 255) / 256, 256, 0, stream>>>(ii, NEDGES, eoffs, counts, esorted);
    }

    const int EGRID = (NEDGES + 127) / 128;            // emb_chain
    const int EW    = (NEDGES / 16 + 3) / 4;           // wave-tiled E kernels (1563)
    const int AW    = (NATOMS / 16 + 3) / 4;           // atom chain (125)
    const int GW    = (NATOMS / 2 + 3) / 4;            // gather (1000)
    auto out_block = [&](int k) {
        gatherT_k<<<GW, 256, 0, stream>>>(
            Xb, rbf, out_rbf_w + (size_t)k * NRR * HD, eoffs, esorted, TA, NATOMS);
        atomchain_w<<<AW, 256, 0, stream>>>(
            TA, w128 + (size_t)(OFF_OUTL + 3 * k) * MSZ,
            out_lins_b + (size_t)k * 3 * HD, out_w + (size_t)k * HD, P_atom, NATOMS);
    };

    // ---------------- Embedding ----------------
    emb_lin_k<<<95, HD, 0, stream>>>(emb_table, emb_w, A0, A1);
    emb_chain_k<<<EGRID, 256, 0, stream>>>(
        rbf, emb_rbf_w, emb_rbf_b, w128 + (size_t)OFF_EMB * MSZ,
        A0, A1, emb_b, z, ii, jj, bufA, Xb, NEDGES);

    zero(P_atom, NATOMS);
    out_block(0);

    // ---------------- Interaction blocks ----------------
    for (int b = 0; b < NBLKS; ++b) {
        sbf_proj_s<<<(NTRIP + 255) / 256, 256, 0, stream>>>(
            sbf, int_sbf_w + (size_t)b * NSNR * NBB, tpos, sps);

        kjcb_w<<<EW, 256, 0, stream>>>(
            Xb, w128 + (size_t)(OFF_KJ + b) * MSZ, int_kj_b + (size_t)b * HD,
            rbf, int_rbf_w + (size_t)b * NRR * HD, Cb, NEDGES);

        megatrip_w<<<EW, 256, 0, stream>>>(
            Xb, Cb, sps, toffs, ekjs,
            wM + (size_t)b * HD * 1024,
            w128 + (size_t)(OFF_JI + b) * MSZ, int_ji_b + (size_t)b * HD,
            w128 + (size_t)(OFF_CHAIN + b * 7) * MSZ, bc + (size_t)b * 7 * HD,
            bufA, Xb, NEDGES);

        out_block(b + 1);
    }

    // ---------------- Final graph reduction ----------------
    zero(d_outf, NGRAPH);
    graph_sum_k<<<(NATOMS + 255) / 256, 256, 0, stream>>>(P_atom, batch, d_outf);
}

// Round 10
// 5175.696 us; speedup vs baseline: 1.3761x; 1.3761x over previous
//
#include <hip/hip_runtime.h>
#include <cstdint>
#include <cstddef>

typedef unsigned short ushort_t;
typedef unsigned int uint_t;

#define NATOMS 8000
#define NEDGES 100000
#define NTRIP  500000
#define NGRAPH 64
#define HD     128
#define NRR    6
#define NSNR   42
#define NBB    8
#define NBLKS  6
#define MSZ    16384

using short8   = __attribute__((ext_vector_type(8))) short;
using ushort8v = __attribute__((ext_vector_type(8))) unsigned short;
using floatx4  = __attribute__((ext_vector_type(4))) float;

__device__ __forceinline__ float siluf(float x){ return x / (1.f + __expf(-x)); }
__device__ __forceinline__ ushort_t f2us(float f){
    uint_t u = __builtin_bit_cast(uint_t, f);
    u = (u + 0x7FFFu + ((u >> 16) & 1u)) >> 16;
    return (ushort_t)u;
}
__device__ __forceinline__ float us2f(ushort_t s){
    uint_t u = ((uint_t)s) << 16;
    return __builtin_bit_cast(float, u);
}
__device__ __forceinline__ void wave_lds_fence(){
    asm volatile("s_waitcnt lgkmcnt(0)" ::: "memory");
}

__global__ void zerof_k(float* __restrict__ p, int n){ int i=blockIdx.x*256+threadIdx.x; if(i<n) p[i]=0.f; }
__global__ void zeroi_k(int* __restrict__ p, int n){ int i=blockIdx.x*256+threadIdx.x; if(i<n) p[i]=0; }

// ---------------- weight prep ----------------
__global__ __launch_bounds__(256)
void transp128_k(const float* __restrict__ src, ushort_t* __restrict__ dst)
{
    __shared__ ushort_t L[128][130];
    int m = blockIdx.x;
    const float* S = src + (size_t)m * MSZ;
    ushort_t* D = dst + (size_t)m * MSZ;
    int tid = threadIdx.x;
    #pragma unroll
    for (int p = 0; p < 64; ++p) {
        int idx = p * 256 + tid;
        int k = idx >> 7, n = idx & 127;
        L[k][n] = f2us(S[idx]);
    }
    __syncthreads();
    #pragma unroll
    for (int p = 0; p < 64; ++p) {
        int idx = p * 256 + tid;
        int n = idx >> 7, k = idx & 127;
        D[idx] = L[k][n];
    }
}

__global__ void castWM_k(const float* __restrict__ src, ushort_t* __restrict__ dst, int n)
{
    int i = blockIdx.x * 256 + threadIdx.x;
    if (i < n) dst[i] = f2us(src[i]);
}

__global__ void pack_bc_k(const float* __restrict__ bef, const float* __restrict__ lin,
                          const float* __restrict__ aft, float* __restrict__ bc)
{
    int b = blockIdx.x;
    for (int i = threadIdx.x; i < 7 * HD; i += 256) {
        int s = i >> 7, h = i & 127;
        float v;
        if (s < 2)      v = bef[(size_t)(b * 2 + s) * HD + h];
        else if (s == 2) v = lin[(size_t)b * HD + h];
        else             v = aft[(size_t)(b * 4 + (s - 3)) * HD + h];
        bc[(size_t)b * 7 * HD + i] = v;
    }
}

// ---------------- CSR build ----------------
__global__ void hist_k(const int* __restrict__ idx, int n, int* __restrict__ cnt)
{
    int i = blockIdx.x * 256 + threadIdx.x;
    if (i < n) atomicAdd(&cnt[idx[i]], 1);
}
__global__ void blksum_k(const int* __restrict__ c, int n, int* __restrict__ bs)
{
    int i = blockIdx.x * 256 + threadIdx.x;
    int v = (i < n) ? c[i] : 0;
    #pragma unroll
    for (int off = 32; off; off >>= 1) v += __shfl_down(v, off);
    __shared__ int sh[4];
    if ((threadIdx.x & 63) == 0) sh[threadIdx.x >> 6] = v;
    __syncthreads();
    if (threadIdx.x == 0) bs[blockIdx.x] = sh[0] + sh[1] + sh[2] + sh[3];
}
__global__ void scanb_k(int* __restrict__ bs, int nb)
{
    __shared__ int sh[1024];
    int t = threadIdx.x;
    int v = (t < nb) ? bs[t] : 0;
    sh[t] = v; __syncthreads();
    for (int off = 1; off < 1024; off <<= 1) {
        int u = (t >= off) ? sh[t - off] : 0;
        __syncthreads();
        sh[t] += u;
        __syncthreads();
    }
    if (t < nb) bs[t] = sh[t] - v;
}
__global__ void scanfin_k(const int* __restrict__ c, int n, const int* __restrict__ bs,
                          int* __restrict__ offs)
{
    __shared__ int sh[256];
    int t = threadIdx.x;
    int i = blockIdx.x * 256 + t;
    int v = (i < n) ? c[i] : 0;
    sh[t] = v; __syncthreads();
    for (int off = 1; off < 256; off <<= 1) {
        int u = (t >= off) ? sh[t - off] : 0;
        __syncthreads();
        sh[t] += u;
        __syncthreads();
    }
    if (i < n)  offs[i] = bs[blockIdx.x] + sh[t] - v;
    if (i == n - 1) offs[n] = bs[blockIdx.x] + sh[t];
}
__global__ void fill_k(const int* __restrict__ idx, int n, const int* __restrict__ offs,
                       int* __restrict__ cur, int* __restrict__ sorted)
{
    int i = blockIdx.x * 256 + threadIdx.x;
    if (i >= n) return;
    int e = idx[i];
    int p = offs[e] + atomicAdd(&cur[e], 1);
    sorted[p] = i;
}
__global__ void invperm_k(const int* __restrict__ tsorted, const int* __restrict__ idx_kj,
                          int* __restrict__ tpos, int* __restrict__ ekjs, int n)
{
    int k = blockIdx.x * 256 + threadIdx.x;
    if (k >= n) return;
    int t = tsorted[k];
    tpos[t] = k;
    ekjs[k] = idx_kj[t];
}

// ---------------------------------------------------------------------------
// Legacy block helpers (emb_chain only)
// ---------------------------------------------------------------------------
__device__ __forceinline__ void load_bh(const ushort_t* Bt, int kh, int tid, ushort8v r[4])
{
    #pragma unroll
    for (int p = 0; p < 4; ++p) {
        int c = p * 256 + tid;
        int n = c >> 3, c8 = c & 7;
        r[p] = *(const ushort8v*)(Bt + (size_t)n * 128 + kh * 64 + c8 * 8);
    }
}
__device__ __forceinline__ void store_bh(ushort8v r[4], ushort_t (*Bl)[72], int tid)
{
    #pragma unroll
    for (int p = 0; p < 4; ++p) {
        int c = p * 256 + tid;
        *(ushort8v*)&Bl[c >> 3][(c & 7) * 8] = r[p];
    }
}
__device__ __forceinline__ void mfma_kh(ushort_t (*Al)[136], ushort_t (*Bl)[72],
                                        floatx4 acc[4][4], int kh,
                                        int wr, int wc, int lhi, int llo)
{
    #pragma unroll
    for (int ks = 0; ks < 2; ++ks) {
        int kk = ks * 32 + lhi * 8;
        short8 af[4], bf[4];
        #pragma unroll
        for (int tm = 0; tm < 4; ++tm)
            af[tm] = *(const short8*)&Al[wr * 64 + tm * 16 + llo][kh * 64 + kk];
        #pragma unroll
        for (int tn = 0; tn < 4; ++tn)
            bf[tn] = *(const short8*)&Bl[wc * 64 + tn * 16 + llo][kk];
        #pragma unroll
        for (int tm = 0; tm < 4; ++tm)
            #pragma unroll
            for (int tn = 0; tn < 4; ++tn)
                acc[tm][tn] = __builtin_amdgcn_mfma_f32_16x16x32_bf16(
                    af[tm], bf[tn], acc[tm][tn], 0, 0, 0);
    }
}
#define ZERO_ACC4(acc) { _Pragma("unroll") for (int a_=0;a_<4;++a_) _Pragma("unroll") \
    for (int b_=0;b_<4;++b_) _Pragma("unroll") for (int q_=0;q_<4;++q_) acc[a_][b_][q_]=0.f; }
#define ZERO_ACC8(acc) { _Pragma("unroll") for (int t_=0;t_<8;++t_) { acc[t_][0]=0.f; acc[t_][1]=0.f; acc[t_][2]=0.f; acc[t_][3]=0.f; } }

// ---------------------------------------------------------------------------
// Embedding chain (block-tiled, validated)
// ---------------------------------------------------------------------------
__global__ __launch_bounds__(256)
void emb_chain_k(const float* __restrict__ rbf, const float* __restrict__ W6g,
                 const float* __restrict__ b6g, const ushort_t* __restrict__ Wemb3,
                 const float* __restrict__ A0, const float* __restrict__ A1,
                 const float* __restrict__ emb_b, const int* __restrict__ z,
                 const int* __restrict__ ii, const int* __restrict__ jj,
                 float* __restrict__ X, ushort_t* __restrict__ Xb, int M)
{
    __shared__ ushort_t Al[128][136];
    __shared__ ushort_t Bl[128][72];
    __shared__ float W6[NRR * HD];
    __shared__ float b6s[HD];
    const int tid = threadIdx.x, row0 = blockIdx.x * 128;
    const int wave = tid >> 6, lane = tid & 63;
    const int wr = wave >> 1, wc_ = wave & 1, lhi = lane >> 4, llo = lane & 15;

    for (int i = tid; i < NRR * HD; i += 256) W6[i] = W6g[i];
    if (tid < HD) b6s[tid] = b6g[tid];
    ushort8v r0[4], r1[4];
    load_bh(Wemb3, 0, tid, r0); load_bh(Wemb3, 1, tid, r1);
    __syncthreads();

    {
        int e_l = tid >> 1, half = tid & 1;
        int grow = row0 + e_l; if (grow >= M) grow = M - 1;
        float r6[NRR];
        #pragma unroll
        for (int r = 0; r < NRR; ++r) r6[r] = rbf[(size_t)grow * NRR + r];
        #pragma unroll 8
        for (int hh = 0; hh < 64; ++hh) {
            int h = half * 64 + hh;
            float a = b6s[h];
            #pragma unroll
            for (int r = 0; r < NRR; ++r) a += r6[r] * W6[r * HD + h];
            Al[e_l][h] = f2us(siluf(a));
        }
    }
    __syncthreads();

    floatx4 acc[4][4]; ZERO_ACC4(acc);
    store_bh(r0, Bl, tid); __syncthreads();
    mfma_kh(Al, Bl, acc, 0, wr, wc_, lhi, llo);
    __syncthreads();
    store_bh(r1, Bl, tid); __syncthreads();
    mfma_kh(Al, Bl, acc, 1, wr, wc_, lhi, llo);

    #pragma unroll
    for (int tm = 0; tm < 4; ++tm)
        #pragma unroll
        for (int q = 0; q < 4; ++q) {
            int grow = row0 + wr * 64 + tm * 16 + lhi * 4 + q;
            if (grow >= M) continue;
            int zi = z[ii[grow]], zj = z[jj[grow]];
            #pragma unroll
            for (int tn = 0; tn < 4; ++tn) {
                int coll = wc_ * 64 + tn * 16 + llo;
                float t = acc[tm][tn][q] + A0[zi * HD + coll] + A1[zj * HD + coll] + emb_b[coll];
                float v = siluf(t);
                size_t o = (size_t)grow * HD + coll;
                X[o] = v; Xb[o] = f2us(v);
            }
        }
}

// ---------------------------------------------------------------------------
// kjcb: Cb = bf16( silu(x@Wkj+b) * rbfp )
// ---------------------------------------------------------------------------
__global__ __launch_bounds__(256, 3)
void kjcb_w(const ushort_t* __restrict__ Xb, const ushort_t* __restrict__ Wkj,
            const float* __restrict__ bkj, const float* __restrict__ rbf,
            const float* __restrict__ Wr6, ushort_t* __restrict__ Cb, int M)
{
    __shared__ float W6s[NRR * HD];
    __shared__ float bkjS[HD];
    const int tid = threadIdx.x, wave = tid >> 6, lane = tid & 63;
    const int llo = lane & 15, lhi = lane >> 4;
    for (int i = tid; i < NRR * HD; i += 256) W6s[i] = Wr6[i];
    if (tid < HD) bkjS[tid] = bkj[tid];
    __syncthreads();
    const int row0 = (blockIdx.x * 4 + wave) * 16;
    if (row0 >= M) return;

    short8 af[4];
    #pragma unroll
    for (int kc = 0; kc < 4; ++kc)
        af[kc] = *(const short8*)(Xb + (size_t)(row0 + llo) * HD + kc * 32 + lhi * 8);

    float rb[4][NRR];
    {
        const float* rp = rbf + (size_t)(row0 + lhi * 4) * NRR;
        #pragma unroll
        for (int q = 0; q < 4; ++q)
            #pragma unroll
            for (int r = 0; r < NRR; ++r) rb[q][r] = rp[q * NRR + r];
    }

    floatx4 acc[8]; ZERO_ACC8(acc);
    #pragma unroll
    for (int kc = 0; kc < 4; ++kc) {
        short8 bq[8];
        #pragma unroll
        for (int tn = 0; tn < 8; ++tn)
            bq[tn] = *(const short8*)(Wkj + (size_t)(tn * 16 + llo) * HD + kc * 32 + lhi * 8);
        #pragma unroll
        for (int tn = 0; tn < 8; ++tn)
            acc[tn] = __builtin_amdgcn_mfma_f32_16x16x32_bf16(af[kc], bq[tn], acc[tn], 0, 0, 0);
    }
    #pragma unroll
    for (int tn = 0; tn < 8; ++tn) {
        int col = tn * 16 + llo;
        #pragma unroll
        for (int q = 0; q < 4; ++q) {
            int grow = row0 + lhi * 4 + q;
            if (grow >= M) continue;
            float rpv = 0.f;
            #pragma unroll
            for (int r = 0; r < NRR; ++r) rpv += rb[q][r] * W6s[r * HD + col];
            Cb[(size_t)grow * HD + col] = f2us(siluf(acc[tn][q] + bkjS[col]) * rpv);
        }
    }
}

// ---------------------------------------------------------------------------
// Triplet accumulate (r8 shape + sorted sps/ekjs): one Cb read per triplet,
// 8 j-accumulators per (e,h) thread. G[e-c0][j*128+h] bf16.
// ---------------------------------------------------------------------------
__global__ __launch_bounds__(256)
void trip_accum_k(const ushort_t* __restrict__ sps, const ushort_t* __restrict__ Cb,
                  const int* __restrict__ toffs, const int* __restrict__ ekjs,
                  ushort_t* __restrict__ G, int c0, int c1)
{
    int e = c0 + blockIdx.x * 2 + (threadIdx.x >> 7);
    if (e >= c1) return;
    int h = threadIdx.x & 127;
    float acc[NBB];
    #pragma unroll
    for (int j = 0; j < NBB; ++j) acc[j] = 0.f;
    int k1 = toffs[e + 1];
    for (int k = toffs[e]; k < k1; ++k) {
        int ekj = ekjs[k];
        float v = us2f(Cb[(size_t)ekj * HD + h]);
        ushort8v s8 = *(const ushort8v*)(sps + (size_t)k * NBB);   // sequential in k
        #pragma unroll
        for (int j = 0; j < NBB; ++j) acc[j] += us2f(s8[j]) * v;
    }
    ushort_t* g = G + (size_t)(e - c0) * 1024 + h;
    #pragma unroll
    for (int j = 0; j < NBB; ++j) g[j * HD] = f2us(acc[j]);
}

// ---------------------------------------------------------------------------
// megaK: per wave 16 edge rows:
//   phase1: K=1024 GEMM from G (streaming, L3-hot) -> macc
//   phase2: x_ji GEMM from Xb -> hin = x_ji + macc
//   phase3: 7-step mega chain in registers -> X fp32 + Xb bf16 (written once)
// ---------------------------------------------------------------------------
__global__ __launch_bounds__(256, 3)
void megaK_w(const ushort_t* __restrict__ G, const ushort_t* __restrict__ Xb,
             const ushort_t* __restrict__ Wm,      // [128][1024]
             const ushort_t* __restrict__ Wji, const float* __restrict__ bjig,
             const ushort_t* __restrict__ Wc, const float* __restrict__ Bc,
             float* __restrict__ X, ushort_t* __restrict__ Xbo, int c0, int c1)
{
    __shared__ float bjiS[HD];
    __shared__ float bs[7 * HD];
    __shared__ ushort_t T[4][16][136];
    const int tid = threadIdx.x, wave = tid >> 6, lane = tid & 63;
    const int llo = lane & 15, lhi = lane >> 4;
    if (tid < HD) bjiS[tid] = bjig[tid];
    for (int i = tid; i < 7 * HD; i += 256) bs[i] = Bc[i];
    __syncthreads();
    const int row0 = c0 + (blockIdx.x * 4 + wave) * 16;
    if (row0 >= c1) return;
    ushort_t (*Tw)[136] = T[wave];

    // ---------- phase 1: K=1024 GEMM from G ----------
    floatx4 macc[8]; ZERO_ACC8(macc);
    {
        const ushort_t* ga = G + (size_t)(row0 - c0 + llo) * 1024;
        for (int kc = 0; kc < 32; ++kc) {
            short8 a8 = *(const short8*)(ga + kc * 32 + lhi * 8);
            short8 bq[8];
            #pragma unroll
            for (int tn = 0; tn < 8; ++tn)
                bq[tn] = *(const short8*)(Wm + (size_t)(tn * 16 + llo) * 1024 + kc * 32 + lhi * 8);
            #pragma unroll
            for (int tn = 0; tn < 8; ++tn)
                macc[tn] = __builtin_amdgcn_mfma_f32_16x16x32_bf16(a8, bq[tn], macc[tn], 0, 0, 0);
        }
    }

    // ---------- phase 2: x_ji GEMM, hin = x_ji + m ----------
    float hin[8][4];
    {
        short8 af[4];
        #pragma unroll
        for (int kc = 0; kc < 4; ++kc)
            af[kc] = *(const short8*)(Xb + (size_t)(row0 + llo) * HD + kc * 32 + lhi * 8);
        floatx4 acc[8]; ZERO_ACC8(acc);
        #pragma unroll
        for (int kc = 0; kc < 4; ++kc) {
            short8 bq[8];
            #pragma unroll
            for (int tn = 0; tn < 8; ++tn)
                bq[tn] = *(const short8*)(Wji + (size_t)(tn * 16 + llo) * HD + kc * 32 + lhi * 8);
            #pragma unroll
            for (int tn = 0; tn < 8; ++tn)
                acc[tn] = __builtin_amdgcn_mfma_f32_16x16x32_bf16(af[kc], bq[tn], acc[tn], 0, 0, 0);
        }
        #pragma unroll
        for (int tn = 0; tn < 8; ++tn) {
            int col = tn * 16 + llo;
            #pragma unroll
            for (int q = 0; q < 4; ++q)
                hin[tn][q] = siluf(acc[tn][q] + bjiS[col]) + macc[tn][q];
        }
    }

    // ---------- phase 3: mega chain ----------
    float cur[8][4], trunk[8][4];
    #pragma unroll
    for (int tn = 0; tn < 8; ++tn)
        #pragma unroll
        for (int q = 0; q < 4; ++q) cur[tn][q] = hin[tn][q];

    for (int s = 0; s < 7; ++s) {
        #pragma unroll
        for (int tn = 0; tn < 8; ++tn)
            #pragma unroll
            for (int q = 0; q < 4; ++q)
                Tw[lhi * 4 + q][tn * 16 + llo] = f2us(cur[tn][q]);
        wave_lds_fence();

        const ushort_t* W = Wc + (size_t)s * MSZ;
        floatx4 acc[8]; ZERO_ACC8(acc);
        #pragma unroll
        for (int kc = 0; kc < 4; ++kc) {
            short8 a8 = *(const short8*)&Tw[llo][kc * 32 + lhi * 8];
            short8 bq[8];
            #pragma unroll
            for (int tn = 0; tn < 8; ++tn)
                bq[tn] = *(const short8*)(W + (size_t)(tn * 16 + llo) * HD + kc * 32 + lhi * 8);
            #pragma unroll
            for (int tn = 0; tn < 8; ++tn)
                acc[tn] = __builtin_amdgcn_mfma_f32_16x16x32_bf16(a8, bq[tn], acc[tn], 0, 0, 0);
        }
        wave_lds_fence();

        #pragma unroll
        for (int tn = 0; tn < 8; ++tn) {
            int col = tn * 16 + llo;
            #pragma unroll
            for (int q = 0; q < 4; ++q) {
                int grow = row0 + lhi * 4 + q;
                float t = siluf(acc[tn][q] + bs[s * HD + col]);
                if (s == 0)      cur[tn][q] = t;
                else if (s == 1) cur[tn][q] = t + hin[tn][q];
                else if (s == 2) { cur[tn][q] = t + X[(size_t)grow * HD + col]; trunk[tn][q] = cur[tn][q]; }
                else if (s == 3 || s == 5) cur[tn][q] = t;
                else { cur[tn][q] = t + trunk[tn][q]; trunk[tn][q] = cur[tn][q]; }
            }
        }
    }
    #pragma unroll
    for (int tn = 0; tn < 8; ++tn) {
        int col = tn * 16 + llo;
        #pragma unroll
        for (int q = 0; q < 4; ++q) {
            int grow = row0 + lhi * 4 + q;
            if (grow >= c1) continue;
            size_t o = (size_t)grow * HD + col;
            X[o] = cur[tn][q];
            Xbo[o] = f2us(cur[tn][q]);
        }
    }
}

// ---------------------------------------------------------------------------
// Atom-side: wide CSR gather + small chain
// ---------------------------------------------------------------------------
__global__ __launch_bounds__(256)
void gatherT_k(const ushort_t* __restrict__ Xb, const float* __restrict__ rbf,
               const float* __restrict__ Wr6, const int* __restrict__ eoffs,
               const int* __restrict__ esorted, ushort_t* __restrict__ TA, int M)
{
    __shared__ float W6s[NRR * HD];
    const int tid = threadIdx.x, wave = tid >> 6, lane = tid & 63;
    for (int i = tid; i < NRR * HD; i += 256) W6s[i] = Wr6[i];
    __syncthreads();
    int a0 = (blockIdx.x * 4 + wave) * 2;
    #pragma unroll
    for (int s = 0; s < 2; ++s) {
        int a = a0 + s;
        if (a >= M) return;
        float acc0 = 0.f, acc1 = 0.f;
        int k1 = eoffs[a + 1];
        for (int k = eoffs[a]; k < k1; ++k) {
            int e = esorted[k];
            float r6[NRR];
            #pragma unroll
            for (int r = 0; r < NRR; ++r) r6[r] = rbf[(size_t)e * NRR + r];
            float rp0 = 0.f, rp1 = 0.f;
            #pragma unroll
            for (int r = 0; r < NRR; ++r) {
                rp0 += r6[r] * W6s[r * HD + lane];
                rp1 += r6[r] * W6s[r * HD + 64 + lane];
            }
            acc0 += rp0 * us2f(Xb[(size_t)e * HD + lane]);
            acc1 += rp1 * us2f(Xb[(size_t)e * HD + 64 + lane]);
        }
        TA[(size_t)a * HD + lane] = f2us(acc0);
        TA[(size_t)a * HD + 64 + lane] = f2us(acc1);
    }
}

__global__ __launch_bounds__(256, 3)
void atomchain_w(const ushort_t* __restrict__ TA, const ushort_t* __restrict__ Wl,
                 const float* __restrict__ bl, const float* __restrict__ wout,
                 float* __restrict__ P, int M)
{
    __shared__ float blS[3 * HD];
    __shared__ float woS[HD];
    __shared__ ushort_t T[4][16][136];
    const int tid = threadIdx.x, wave = tid >> 6, lane = tid & 63;
    const int llo = lane & 15, lhi = lane >> 4;
    for (int i = tid; i < 3 * HD; i += 256) blS[i] = bl[i];
    if (tid < HD) woS[tid] = wout[tid];
    __syncthreads();
    const int row0 = (blockIdx.x * 4 + wave) * 16;
    if (row0 >= M) return;
    ushort_t (*Tw)[136] = T[wave];

    #pragma unroll
    for (int s = 0; s < 3; ++s) {
        short8 af[4];
        if (s == 0) {
            #pragma unroll
            for (int kc = 0; kc < 4; ++kc)
                af[kc] = *(const short8*)(TA + (size_t)(row0 + llo) * HD + kc * 32 + lhi * 8);
        } else {
            #pragma unroll
            for (int kc = 0; kc < 4; ++kc)
                af[kc] = *(const short8*)&Tw[llo][kc * 32 + lhi * 8];
        }
        const ushort_t* W = Wl + (size_t)s * MSZ;
        floatx4 acc[8]; ZERO_ACC8(acc);
        #pragma unroll
        for (int kc = 0; kc < 4; ++kc) {
            short8 bq[8];
            #pragma unroll
            for (int tn = 0; tn < 8; ++tn)
                bq[tn] = *(const short8*)(W + (size_t)(tn * 16 + llo) * HD + kc * 32 + lhi * 8);
            #pragma unroll
            for (int tn = 0; tn < 8; ++tn)
                acc[tn] = __builtin_amdgcn_mfma_f32_16x16x32_bf16(af[kc], bq[tn], acc[tn], 0, 0, 0);
        }
        if (s < 2) {
            wave_lds_fence();
            #pragma unroll
            for (int tn = 0; tn < 8; ++tn) {
                int col = tn * 16 + llo;
                #pragma unroll
                for (int q = 0; q < 4; ++q)
                    Tw[lhi * 4 + q][col] = f2us(siluf(acc[tn][q] + blS[s * HD + col]));
            }
            wave_lds_fence();
        } else {
            #pragma unroll
            for (int q = 0; q < 4; ++q) {
                float v = 0.f;
                #pragma unroll
                for (int tn = 0; tn < 8; ++tn) {
                    int col = tn * 16 + llo;
                    v += siluf(acc[tn][q] + blS[2 * HD + col]) * woS[col];
                }
                v += __shfl_xor(v, 1); v += __shfl_xor(v, 2);
                v += __shfl_xor(v, 4); v += __shfl_xor(v, 8);
                int a = row0 + lhi * 4 + q;
                if (llo == 0 && a < M) P[a] += v;
            }
        }
    }
}

// ---------------- small kernels ----------------
__global__ void emb_lin_k(const float* __restrict__ emb_table, const float* __restrict__ emb_w,
                          float* __restrict__ A0, float* __restrict__ A1)
{
    __shared__ float er[HD];
    int a = blockIdx.x, h = threadIdx.x;
    er[h] = emb_table[a * HD + h];
    __syncthreads();
    float acc0 = 0.f, acc1 = 0.f;
    #pragma unroll 8
    for (int l = 0; l < HD; ++l) {
        float e = er[l];
        acc0 += e * emb_w[l * HD + h];
        acc1 += e * emb_w[(HD + l) * HD + h];
    }
    A0[a * HD + h] = acc0;
    A1[a * HD + h] = acc1;
}

__global__ void sbf_proj_s(const float* __restrict__ sbf, const float* __restrict__ W,
                           const int* __restrict__ tpos, ushort_t* __restrict__ sps)
{
    __shared__ float Ws[NSNR * NBB];
    for (int s = threadIdx.x; s < NSNR * NBB; s += 256) Ws[s] = W[s];
    __syncthreads();
    int t = blockIdx.x * 256 + threadIdx.x;
    if (t >= NTRIP) return;
    float acc[NBB];
    #pragma unroll
    for (int n = 0; n < NBB; ++n) acc[n] = 0.f;
    #pragma unroll
    for (int r = 0; r < NSNR; ++r) {
        float v = sbf[(size_t)t * NSNR + r];
        #pragma unroll
        for (int n = 0; n < NBB; ++n) acc[n] += v * Ws[r * NBB + n];
    }
    int p = tpos[t];
    ushort_t* o = sps + (size_t)p * NBB;
    #pragma unroll
    for (int n = 0; n < NBB; ++n) o[n] = f2us(acc[n]);
}

__global__ void graph_sum_k(const float* __restrict__ P, const int* __restrict__ batch,
                            float* __restrict__ outg)
{
    int a = blockIdx.x * 256 + threadIdx.x;
    if (a >= NATOMS) return;
    atomicAdd(&outg[batch[a]], P[a]);
}

// ---------------------------------------------------------------------------
extern "C" void kernel_launch(void* const* d_in, const int* in_sizes, int n_in,
                              void* d_out, int out_size, void* d_ws, size_t ws_size,
                              hipStream_t stream)
{
    const int*   z         = (const int*)  d_in[0];
    const float* rbf       = (const float*)d_in[1];
    const float* sbf       = (const float*)d_in[2];
    const int*   ii        = (const int*)  d_in[3];
    const int*   jj        = (const int*)  d_in[4];
    const int*   idx_kj    = (const int*)  d_in[5];
    const int*   idx_ji    = (const int*)  d_in[6];
    const int*   batch     = (const int*)  d_in[7];
    const float* emb_table = (const float*)d_in[8];
    const float* emb_rbf_w = (const float*)d_in[9];
    const float* emb_rbf_b = (const float*)d_in[10];
    const float* emb_w     = (const float*)d_in[11];
    const float* emb_b     = (const float*)d_in[12];
    const float* int_rbf_w = (const float*)d_in[13];
    const float* int_sbf_w = (const float*)d_in[14];
    const float* int_kj_w  = (const float*)d_in[15];
    const float* int_kj_b  = (const float*)d_in[16];
    const float* int_ji_w  = (const float*)d_in[17];
    const float* int_ji_b  = (const float*)d_in[18];
    const float* int_W     = (const float*)d_in[19];
    const float* int_bef_w = (const float*)d_in[20];
    const float* int_bef_b = (const float*)d_in[21];
    const float* int_lin_w = (const float*)d_in[22];
    const float* int_lin_b = (const float*)d_in[23];
    const float* int_aft_w = (const float*)d_in[24];
    const float* int_aft_b = (const float*)d_in[25];
    const float* out_rbf_w = (const float*)d_in[26];
    const float* out_lins_w= (const float*)d_in[27];
    const float* out_lins_b= (const float*)d_in[28];
    const float* out_w     = (const float*)d_in[29];
    float* d_outf          = (float*)d_out;

    const size_t EH = (size_t)NEDGES * HD;
    const int OFF_EMB = 0, OFF_KJ = 1, OFF_JI = 7, OFF_CHAIN = 13, OFF_OUTL = 55;

    char* base = (char*)d_ws;
    auto take = [&](size_t bytes) { char* p = base; base += (bytes + 255) & ~(size_t)255; return p; };
    float* bufA    = (float*)take(EH * 4);                     // X fp32 trunk
    ushort_t* Xb   = (ushort_t*)take(EH * 2);                  // X bf16 shadow
    ushort_t* Cb   = (ushort_t*)take(EH * 2);                  // x_kj bf16
    ushort_t* sps  = (ushort_t*)take((size_t)NTRIP * NBB * 2); // sp, tsorted order
    ushort_t* TA   = (ushort_t*)take((size_t)NATOMS * HD * 2);
    float* P_atom  = (float*)take((size_t)NATOMS * 4);
    float* A0      = (float*)take(95 * HD * 4);
    float* A1      = (float*)take(95 * HD * 4);
    float* bc      = (float*)take((size_t)NBLKS * 7 * HD * 4);
    int*   counts  = (int*)  take((size_t)(NEDGES + 1) * 4);
    int*   bsum    = (int*)  take(1024 * 4);
    int*   toffs   = (int*)  take((size_t)(NEDGES + 1) * 4);
    int*   eoffs   = (int*)  take((size_t)(NATOMS + 1) * 4);
    int*   tsorted = (int*)  take((size_t)NTRIP * 4);
    int*   esorted = (int*)  take((size_t)NEDGES * 4);
    int*   tpos    = (int*)  take((size_t)NTRIP * 4);
    int*   ekjs    = (int*)  take((size_t)NTRIP * 4);
    ushort_t* w128 = (ushort_t*)take((size_t)76 * MSZ * 2);
    ushort_t* wM   = (ushort_t*)take((size_t)NBLKS * HD * 1024 * 2);
    size_t fixed   = (size_t)(base - (char*)d_ws);
    ushort_t* G    = (ushort_t*)base;

    // adaptive chunking of G (chunk rows multiple of 16; NEDGES % 16 == 0)
    int nch = 8;
    for (int c = 1; c <= 8; ++c) {
        int ch = ((NEDGES + c - 1) / c + 15) & ~15;
        size_t gb = (size_t)ch * 1024 * 2;
        if (fixed + gb <= ws_size) { nch = c; break; }
    }
    const int CH = ((NEDGES + nch - 1) / nch + 15) & ~15;

    auto zero = [&](float* p, size_t n) {
        zerof_k<<<((int)n + 255) / 256, 256, 0, stream>>>(p, (int)n);
    };

    // ---------------- weight prep ----------------
    transp128_k<<< 1, 256, 0, stream>>>(emb_w + 2 * MSZ, w128 + (size_t)OFF_EMB * MSZ);
    transp128_k<<< 6, 256, 0, stream>>>(int_kj_w,   w128 + (size_t)OFF_KJ  * MSZ);
    transp128_k<<< 6, 256, 0, stream>>>(int_ji_w,   w128 + (size_t)OFF_JI  * MSZ);
    for (int b = 0; b < NBLKS; ++b) {
        transp128_k<<<2, 256, 0, stream>>>(int_bef_w + (size_t)b * 2 * MSZ,
                                           w128 + (size_t)(OFF_CHAIN + b * 7) * MSZ);
        transp128_k<<<1, 256, 0, stream>>>(int_lin_w + (size_t)b * MSZ,
                                           w128 + (size_t)(OFF_CHAIN + b * 7 + 2) * MSZ);
        transp128_k<<<4, 256, 0, stream>>>(int_aft_w + (size_t)b * 4 * MSZ,
                                           w128 + (size_t)(OFF_CHAIN + b * 7 + 3) * MSZ);
    }
    transp128_k<<<21, 256, 0, stream>>>(out_lins_w, w128 + (size_t)OFF_OUTL * MSZ);
    castWM_k<<<(NBLKS * HD * 1024 + 255) / 256, 256, 0, stream>>>(int_W, wM, NBLKS * HD * 1024);
    pack_bc_k<<<NBLKS, 256, 0, stream>>>(int_bef_b, int_lin_b, int_aft_b, bc);

    // ---------------- CSR builds ----------------
    {
        zeroi_k<<<(NEDGES + 255) / 256, 256, 0, stream>>>(counts, NEDGES);
        hist_k<<<(NTRIP + 255) / 256, 256, 0, stream>>>(idx_ji, NTRIP, counts);
        int nb = (NEDGES + 255) / 256;
        blksum_k<<<nb, 256, 0, stream>>>(counts, NEDGES, bsum);
        scanb_k<<<1, 1024, 0, stream>>>(bsum, nb);
        scanfin_k<<<nb, 256, 0, stream>>>(counts, NEDGES, bsum, toffs);
        zeroi_k<<<(NEDGES + 255) / 256, 256, 0, stream>>>(counts, NEDGES);
        fill_k<<<(NTRIP + 255) / 256, 256, 0, stream>>>(idx_ji, NTRIP, toffs, counts, tsorted);
        invperm_k<<<(NTRIP + 255) / 256, 256, 0, stream>>>(tsorted, idx_kj, tpos, ekjs, NTRIP);
    }
    {
        zeroi_k<<<(NATOMS + 255) / 256, 256, 0, stream>>>(counts, NATOMS);
        hist_k<<<(NEDGES + 255) / 256, 256, 0, stream>>>(ii, NEDGES, counts);
        int nb = (NATOMS + 255) / 256;
        blksum_k<<<nb, 256, 0, stream>>>(counts, NATOMS, bsum);
        scanb_k<<<1, 1024, 0, stream>>>(bsum, nb);
        scanfin_k<<<nb, 256, 0, stream>>>(counts, NATOMS, bsum, eoffs);
        zeroi_k<<<(NATOMS + 255) / 256, 256, 0, stream>>>(counts, NATOMS);
        fill_k<<<(NEDGES + 255) / 256, 256, 0, stream>>>(ii, NEDGES, eoffs, counts, esorted);
    }

    const int EGRID = (NEDGES + 127) / 128;
    const int EW    = (NEDGES / 16 + 3) / 4;
    const int AW    = (NATOMS / 16 + 3) / 4;
    const int GW    = (NATOMS / 2 + 3) / 4;
    auto out_block = [&](int k) {
        gatherT_k<<<GW, 256, 0, stream>>>(
            Xb, rbf, out_rbf_w + (size_t)k * NRR * HD, eoffs, esorted, TA, NATOMS);
        atomchain_w<<<AW, 256, 0, stream>>>(
            TA, w128 + (size_t)(OFF_OUTL + 3 * k) * MSZ,
            out_lins_b + (size_t)k * 3 * HD, out_w + (size_t)k * HD, P_atom, NATOMS);
    };

    // ---------------- Embedding ----------------
    emb_lin_k<<<95, HD, 0, stream>>>(emb_table, emb_w, A0, A1);
    emb_chain_k<<<EGRID, 256, 0, stream>>>(
        rbf, emb_rbf_w, emb_rbf_b, w128 + (size_t)OFF_EMB * MSZ,
        A0, A1, emb_b, z, ii, jj, bufA, Xb, NEDGES);

    zero(P_atom, NATOMS);
    out_block(0);

    // ---------------- Interaction blocks ----------------
    for (int b = 0; b < NBLKS; ++b) {
        sbf_proj_s<<<(NTRIP + 255) / 256, 256, 0, stream>>>(
            sbf, int_sbf_w + (size_t)b * NSNR * NBB, tpos, sps);

        kjcb_w<<<EW, 256, 0, stream>>>(
            Xb, w128 + (size_t)(OFF_KJ + b) * MSZ, int_kj_b + (size_t)b * HD,
            rbf, int_rbf_w + (size_t)b * NRR * HD, Cb, NEDGES);

        for (int c = 0; c < nch; ++c) {
            int c0 = c * CH;
            int c1 = (c0 + CH < NEDGES) ? c0 + CH : NEDGES;
            if (c0 >= c1) break;
            int ne = c1 - c0;
            trip_accum_k<<<(ne + 1) / 2, 256, 0, stream>>>(
                sps, Cb, toffs, ekjs, G, c0, c1);
            int gw = ((ne + 15) / 16 + 3) / 4;
            megaK_w<<<gw, 256, 0, stream>>>(
                G, Xb, wM + (size_t)b * HD * 1024,
                w128 + (size_t)(OFF_JI + b) * MSZ, int_ji_b + (size_t)b * HD,
                w128 + (size_t)(OFF_CHAIN + b * 7) * MSZ, bc + (size_t)b * 7 * HD,
                bufA, Xb, c0, c1);
        }

        out_block(b + 1);
    }

    // ---------------- Final graph reduction ----------------
    zero(d_outf, NGRAPH);
    graph_sum_k<<<(NATOMS + 255) / 256, 256, 0, stream>>>(P_atom, batch, d_outf);
}

// Round 11
// 3986.024 us; speedup vs baseline: 1.7868x; 1.2985x over previous
//
#include <hip/hip_runtime.h>
#include <cstdint>
#include <cstddef>

typedef unsigned short ushort_t;
typedef unsigned int uint_t;

#define NATOMS 8000
#define NEDGES 100000
#define NTRIP  500000
#define NGRAPH 64
#define HD     128
#define NRR    6
#define NSNR   42
#define NBB    8
#define NBLKS  6
#define MSZ    16384

using short8   = __attribute__((ext_vector_type(8))) short;
using ushort8v = __attribute__((ext_vector_type(8))) unsigned short;
using floatx4  = __attribute__((ext_vector_type(4))) float;

__device__ __forceinline__ float siluf(float x){ return x / (1.f + __expf(-x)); }
__device__ __forceinline__ ushort_t f2us(float f){
    uint_t u = __builtin_bit_cast(uint_t, f);
    u = (u + 0x7FFFu + ((u >> 16) & 1u)) >> 16;
    return (ushort_t)u;
}
__device__ __forceinline__ float us2f(ushort_t s){
    uint_t u = ((uint_t)s) << 16;
    return __builtin_bit_cast(float, u);
}
__device__ __forceinline__ void wave_lds_fence(){
    asm volatile("s_waitcnt lgkmcnt(0)" ::: "memory");
}
// fragment-order weight load: frag = kc*8+tn, 64 lanes x 16B contiguous
__device__ __forceinline__ short8 ldfrag(const ushort_t* W, int frag, int lane){
    return *(const short8*)(W + ((size_t)(frag * 64 + lane) << 3));
}

__global__ void zerof_k(float* __restrict__ p, int n){ int i=blockIdx.x*256+threadIdx.x; if(i<n) p[i]=0.f; }
__global__ void zeroi_k(int* __restrict__ p, int n){ int i=blockIdx.x*256+threadIdx.x; if(i<n) p[i]=0; }

// ---------------- weight prep ----------------
// classic [n][k] layout (emb_chain only)
__global__ __launch_bounds__(256)
void transp128_k(const float* __restrict__ src, ushort_t* __restrict__ dst)
{
    __shared__ ushort_t L[128][130];
    int m = blockIdx.x;
    const float* S = src + (size_t)m * MSZ;
    ushort_t* D = dst + (size_t)m * MSZ;
    int tid = threadIdx.x;
    #pragma unroll
    for (int p = 0; p < 64; ++p) {
        int idx = p * 256 + tid;
        int k = idx >> 7, n = idx & 127;
        L[k][n] = f2us(S[idx]);
    }
    __syncthreads();
    #pragma unroll
    for (int p = 0; p < 64; ++p) {
        int idx = p * 256 + tid;
        int n = idx >> 7, k = idx & 127;
        D[idx] = L[k][n];
    }
}

// swizzled fragment order for wave-autonomous kernels (K=128):
// dst[(((k>>5)*8 + (n>>4))*64 + ((k>>3)&3)*16 + (n&15))*8 + (k&7)] = src[k][n]
__global__ __launch_bounds__(256)
void transp128s_k(const float* __restrict__ src, ushort_t* __restrict__ dst)
{
    int m = blockIdx.x;
    const float* S = src + (size_t)m * MSZ;
    ushort_t* D = dst + (size_t)m * MSZ;
    int tid = threadIdx.x;
    #pragma unroll
    for (int p = 0; p < 64; ++p) {
        int idx = p * 256 + tid;
        int k = idx >> 7, n = idx & 127;
        size_t d = ((size_t)(((k >> 5) * 8 + (n >> 4)) * 64 + ((k >> 3) & 3) * 16 + (n & 15)) << 3)
                   + (k & 7);
        D[d] = f2us(S[idx]);
    }
}

// int_W -> fragment order (K=1024): src flat = b*131072 + n*1024 + k
__global__ void castWMs_k(const float* __restrict__ src, ushort_t* __restrict__ dst, int n)
{
    int i = blockIdx.x * 256 + threadIdx.x;
    if (i >= n) return;
    int b = i >> 17;
    int r = i & 131071;
    int nn = r >> 10, k = r & 1023;
    size_t d = (size_t)b * 131072
             + ((size_t)(((k >> 5) * 8 + (nn >> 4)) * 64 + ((k >> 3) & 3) * 16 + (nn & 15)) << 3)
             + (k & 7);
    dst[d] = f2us(src[i]);
}

__global__ void pack_bc_k(const float* __restrict__ bef, const float* __restrict__ lin,
                          const float* __restrict__ aft, float* __restrict__ bc)
{
    int b = blockIdx.x;
    for (int i = threadIdx.x; i < 7 * HD; i += 256) {
        int s = i >> 7, h = i & 127;
        float v;
        if (s < 2)      v = bef[(size_t)(b * 2 + s) * HD + h];
        else if (s == 2) v = lin[(size_t)b * HD + h];
        else             v = aft[(size_t)(b * 4 + (s - 3)) * HD + h];
        bc[(size_t)b * 7 * HD + i] = v;
    }
}

// ---------------- CSR build ----------------
__global__ void hist_k(const int* __restrict__ idx, int n, int* __restrict__ cnt)
{
    int i = blockIdx.x * 256 + threadIdx.x;
    if (i < n) atomicAdd(&cnt[idx[i]], 1);
}
__global__ void blksum_k(const int* __restrict__ c, int n, int* __restrict__ bs)
{
    int i = blockIdx.x * 256 + threadIdx.x;
    int v = (i < n) ? c[i] : 0;
    #pragma unroll
    for (int off = 32; off; off >>= 1) v += __shfl_down(v, off);
    __shared__ int sh[4];
    if ((threadIdx.x & 63) == 0) sh[threadIdx.x >> 6] = v;
    __syncthreads();
    if (threadIdx.x == 0) bs[blockIdx.x] = sh[0] + sh[1] + sh[2] + sh[3];
}
__global__ void scanb_k(int* __restrict__ bs, int nb)
{
    __shared__ int sh[1024];
    int t = threadIdx.x;
    int v = (t < nb) ? bs[t] : 0;
    sh[t] = v; __syncthreads();
    for (int off = 1; off < 1024; off <<= 1) {
        int u = (t >= off) ? sh[t - off] : 0;
        __syncthreads();
        sh[t] += u;
        __syncthreads();
    }
    if (t < nb) bs[t] = sh[t] - v;
}
__global__ void scanfin_k(const int* __restrict__ c, int n, const int* __restrict__ bs,
                          int* __restrict__ offs)
{
    __shared__ int sh[256];
    int t = threadIdx.x;
    int i = blockIdx.x * 256 + t;
    int v = (i < n) ? c[i] : 0;
    sh[t] = v; __syncthreads();
    for (int off = 1; off < 256; off <<= 1) {
        int u = (t >= off) ? sh[t - off] : 0;
        __syncthreads();
        sh[t] += u;
        __syncthreads();
    }
    if (i < n)  offs[i] = bs[blockIdx.x] + sh[t] - v;
    if (i == n - 1) offs[n] = bs[blockIdx.x] + sh[t];
}
__global__ void fill_k(const int* __restrict__ idx, int n, const int* __restrict__ offs,
                       int* __restrict__ cur, int* __restrict__ sorted)
{
    int i = blockIdx.x * 256 + threadIdx.x;
    if (i >= n) return;
    int e = idx[i];
    int p = offs[e] + atomicAdd(&cur[e], 1);
    sorted[p] = i;
}
__global__ void invperm_k(const int* __restrict__ tsorted, const int* __restrict__ idx_kj,
                          int* __restrict__ tpos, int* __restrict__ ekjs, int n)
{
    int k = blockIdx.x * 256 + threadIdx.x;
    if (k >= n) return;
    int t = tsorted[k];
    tpos[t] = k;
    ekjs[k] = idx_kj[t];
}

// ---------------------------------------------------------------------------
// Legacy block helpers (emb_chain only)
// ---------------------------------------------------------------------------
__device__ __forceinline__ void load_bh(const ushort_t* Bt, int kh, int tid, ushort8v r[4])
{
    #pragma unroll
    for (int p = 0; p < 4; ++p) {
        int c = p * 256 + tid;
        int n = c >> 3, c8 = c & 7;
        r[p] = *(const ushort8v*)(Bt + (size_t)n * 128 + kh * 64 + c8 * 8);
    }
}
__device__ __forceinline__ void store_bh(ushort8v r[4], ushort_t (*Bl)[72], int tid)
{
    #pragma unroll
    for (int p = 0; p < 4; ++p) {
        int c = p * 256 + tid;
        *(ushort8v*)&Bl[c >> 3][(c & 7) * 8] = r[p];
    }
}
__device__ __forceinline__ void mfma_kh(ushort_t (*Al)[136], ushort_t (*Bl)[72],
                                        floatx4 acc[4][4], int kh,
                                        int wr, int wc, int lhi, int llo)
{
    #pragma unroll
    for (int ks = 0; ks < 2; ++ks) {
        int kk = ks * 32 + lhi * 8;
        short8 af[4], bf[4];
        #pragma unroll
        for (int tm = 0; tm < 4; ++tm)
            af[tm] = *(const short8*)&Al[wr * 64 + tm * 16 + llo][kh * 64 + kk];
        #pragma unroll
        for (int tn = 0; tn < 4; ++tn)
            bf[tn] = *(const short8*)&Bl[wc * 64 + tn * 16 + llo][kk];
        #pragma unroll
        for (int tm = 0; tm < 4; ++tm)
            #pragma unroll
            for (int tn = 0; tn < 4; ++tn)
                acc[tm][tn] = __builtin_amdgcn_mfma_f32_16x16x32_bf16(
                    af[tm], bf[tn], acc[tm][tn], 0, 0, 0);
    }
}
#define ZERO_ACC4(acc) { _Pragma("unroll") for (int a_=0;a_<4;++a_) _Pragma("unroll") \
    for (int b_=0;b_<4;++b_) _Pragma("unroll") for (int q_=0;q_<4;++q_) acc[a_][b_][q_]=0.f; }
#define ZERO_ACC8(acc) { _Pragma("unroll") for (int t_=0;t_<8;++t_) { acc[t_][0]=0.f; acc[t_][1]=0.f; acc[t_][2]=0.f; acc[t_][3]=0.f; } }

// ---------------------------------------------------------------------------
// Embedding chain (block-tiled, classic weight layout)
// ---------------------------------------------------------------------------
__global__ __launch_bounds__(256)
void emb_chain_k(const float* __restrict__ rbf, const float* __restrict__ W6g,
                 const float* __restrict__ b6g, const ushort_t* __restrict__ Wemb3,
                 const float* __restrict__ A0, const float* __restrict__ A1,
                 const float* __restrict__ emb_b, const int* __restrict__ z,
                 const int* __restrict__ ii, const int* __restrict__ jj,
                 float* __restrict__ X, ushort_t* __restrict__ Xb, int M)
{
    __shared__ ushort_t Al[128][136];
    __shared__ ushort_t Bl[128][72];
    __shared__ float W6[NRR * HD];
    __shared__ float b6s[HD];
    const int tid = threadIdx.x, row0 = blockIdx.x * 128;
    const int wave = tid >> 6, lane = tid & 63;
    const int wr = wave >> 1, wc_ = wave & 1, lhi = lane >> 4, llo = lane & 15;

    for (int i = tid; i < NRR * HD; i += 256) W6[i] = W6g[i];
    if (tid < HD) b6s[tid] = b6g[tid];
    ushort8v r0[4], r1[4];
    load_bh(Wemb3, 0, tid, r0); load_bh(Wemb3, 1, tid, r1);
    __syncthreads();

    {
        int e_l = tid >> 1, half = tid & 1;
        int grow = row0 + e_l; if (grow >= M) grow = M - 1;
        float r6[NRR];
        #pragma unroll
        for (int r = 0; r < NRR; ++r) r6[r] = rbf[(size_t)grow * NRR + r];
        #pragma unroll 8
        for (int hh = 0; hh < 64; ++hh) {
            int h = half * 64 + hh;
            float a = b6s[h];
            #pragma unroll
            for (int r = 0; r < NRR; ++r) a += r6[r] * W6[r * HD + h];
            Al[e_l][h] = f2us(siluf(a));
        }
    }
    __syncthreads();

    floatx4 acc[4][4]; ZERO_ACC4(acc);
    store_bh(r0, Bl, tid); __syncthreads();
    mfma_kh(Al, Bl, acc, 0, wr, wc_, lhi, llo);
    __syncthreads();
    store_bh(r1, Bl, tid); __syncthreads();
    mfma_kh(Al, Bl, acc, 1, wr, wc_, lhi, llo);

    #pragma unroll
    for (int tm = 0; tm < 4; ++tm)
        #pragma unroll
        for (int q = 0; q < 4; ++q) {
            int grow = row0 + wr * 64 + tm * 16 + lhi * 4 + q;
            if (grow >= M) continue;
            int zi = z[ii[grow]], zj = z[jj[grow]];
            #pragma unroll
            for (int tn = 0; tn < 4; ++tn) {
                int coll = wc_ * 64 + tn * 16 + llo;
                float t = acc[tm][tn][q] + A0[zi * HD + coll] + A1[zj * HD + coll] + emb_b[coll];
                float v = siluf(t);
                size_t o = (size_t)grow * HD + coll;
                X[o] = v; Xb[o] = f2us(v);
            }
        }
}

// ---------------------------------------------------------------------------
// kjcb: Cb = bf16( silu(x@Wkj+b) * rbfp )   (Wkj in fragment order)
// ---------------------------------------------------------------------------
__global__ __launch_bounds__(256, 3)
void kjcb_w(const ushort_t* __restrict__ Xb, const ushort_t* __restrict__ Wkj,
            const float* __restrict__ bkj, const float* __restrict__ rbf,
            const float* __restrict__ Wr6, ushort_t* __restrict__ Cb, int M)
{
    __shared__ float W6s[NRR * HD];
    __shared__ float bkjS[HD];
    const int tid = threadIdx.x, wave = tid >> 6, lane = tid & 63;
    const int llo = lane & 15, lhi = lane >> 4;
    for (int i = tid; i < NRR * HD; i += 256) W6s[i] = Wr6[i];
    if (tid < HD) bkjS[tid] = bkj[tid];
    __syncthreads();
    const int row0 = (blockIdx.x * 4 + wave) * 16;
    if (row0 >= M) return;

    short8 af[4];
    #pragma unroll
    for (int kc = 0; kc < 4; ++kc)
        af[kc] = *(const short8*)(Xb + (size_t)(row0 + llo) * HD + kc * 32 + lhi * 8);

    float rb[4][NRR];
    {
        const float* rp = rbf + (size_t)(row0 + lhi * 4) * NRR;
        #pragma unroll
        for (int q = 0; q < 4; ++q)
            #pragma unroll
            for (int r = 0; r < NRR; ++r) rb[q][r] = rp[q * NRR + r];
    }

    floatx4 acc[8]; ZERO_ACC8(acc);
    #pragma unroll
    for (int kc = 0; kc < 4; ++kc) {
        short8 bq[8];
        #pragma unroll
        for (int tn = 0; tn < 8; ++tn) bq[tn] = ldfrag(Wkj, kc * 8 + tn, lane);
        #pragma unroll
        for (int tn = 0; tn < 8; ++tn)
            acc[tn] = __builtin_amdgcn_mfma_f32_16x16x32_bf16(af[kc], bq[tn], acc[tn], 0, 0, 0);
    }
    #pragma unroll
    for (int tn = 0; tn < 8; ++tn) {
        int col = tn * 16 + llo;
        #pragma unroll
        for (int q = 0; q < 4; ++q) {
            int grow = row0 + lhi * 4 + q;
            if (grow >= M) continue;
            float rpv = 0.f;
            #pragma unroll
            for (int r = 0; r < NRR; ++r) rpv += rb[q][r] * W6s[r * HD + col];
            Cb[(size_t)grow * HD + col] = f2us(siluf(acc[tn][q] + bkjS[col]) * rpv);
        }
    }
}

// ---------------------------------------------------------------------------
// Triplet accumulate: writes G in A-fragment order.
// element (row = e-c0, k = j*128+h):
//   dst = ((tile*32 + j*4 + (h>>5))*64 + ((h>>3)&3)*16 + ((e-c0)&15))*8 + (h&7)
// ---------------------------------------------------------------------------
__global__ __launch_bounds__(256)
void trip_accum_k(const ushort_t* __restrict__ sps, const ushort_t* __restrict__ Cb,
                  const int* __restrict__ toffs, const int* __restrict__ ekjs,
                  ushort_t* __restrict__ G, int c0, int c1)
{
    int e = c0 + blockIdx.x * 2 + (threadIdx.x >> 7);
    if (e >= c1) return;
    int h = threadIdx.x & 127;
    float acc[NBB];
    #pragma unroll
    for (int j = 0; j < NBB; ++j) acc[j] = 0.f;
    int k1 = toffs[e + 1];
    for (int k = toffs[e]; k < k1; ++k) {
        int ekj = ekjs[k];
        float v = us2f(Cb[(size_t)ekj * HD + h]);
        ushort8v s8 = *(const ushort8v*)(sps + (size_t)k * NBB);
        #pragma unroll
        for (int j = 0; j < NBB; ++j) acc[j] += us2f(s8[j]) * v;
    }
    int rel = e - c0;
    int tile = rel >> 4, el = rel & 15;
    int lhi = (h >> 3) & 3, j8 = h & 7, hc = h >> 5;
    #pragma unroll
    for (int j = 0; j < NBB; ++j) {
        size_t d = ((size_t)((tile * 32 + j * 4 + hc) * 64 + lhi * 16 + el) << 3) + j8;
        G[d] = f2us(acc[j]);
    }
}

// ---------------------------------------------------------------------------
// megaK: per wave 16 edge rows:
//   phase1: K=1024 GEMM from frag-ordered G (register double-buffer)
//   phase2: x_ji GEMM from Xb -> hin = x_ji + macc
//   phase3: 7-step mega chain in registers -> X fp32 + Xb bf16 (written once)
// ---------------------------------------------------------------------------
__global__ __launch_bounds__(256, 3)
void megaK_w(const ushort_t* __restrict__ G, const ushort_t* __restrict__ Xb,
             const ushort_t* __restrict__ Wm,      // frag order, 32 kc
             const ushort_t* __restrict__ Wji, const float* __restrict__ bjig,
             const ushort_t* __restrict__ Wc, const float* __restrict__ Bc,
             float* __restrict__ X, ushort_t* __restrict__ Xbo, int c0, int c1)
{
    __shared__ float bjiS[HD];
    __shared__ float bs[7 * HD];
    __shared__ ushort_t T[4][16][136];
    const int tid = threadIdx.x, wave = tid >> 6, lane = tid & 63;
    const int llo = lane & 15, lhi = lane >> 4;
    if (tid < HD) bjiS[tid] = bjig[tid];
    for (int i = tid; i < 7 * HD; i += 256) bs[i] = Bc[i];
    __syncthreads();
    const int row0 = c0 + (blockIdx.x * 4 + wave) * 16;
    if (row0 >= c1) return;
    ushort_t (*Tw)[136] = T[wave];

    // ---------- phase 1: K=1024 GEMM, register double-buffered ----------
    floatx4 macc[8]; ZERO_ACC8(macc);
    {
        const int tile = (row0 - c0) >> 4;
        const ushort_t* gf = G + ((size_t)(tile * 32) * 64 + lane) * 8;  // + kc*512
        short8 a_n = *(const short8*)gf;
        short8 b_n[8];
        #pragma unroll
        for (int tn = 0; tn < 8; ++tn) b_n[tn] = ldfrag(Wm, tn, lane);
        for (int kc = 0; kc < 32; ++kc) {
            short8 a_c = a_n;
            short8 b_c[8];
            #pragma unroll
            for (int tn = 0; tn < 8; ++tn) b_c[tn] = b_n[tn];
            if (kc < 31) {
                a_n = *(const short8*)(gf + (size_t)(kc + 1) * 512);
                #pragma unroll
                for (int tn = 0; tn < 8; ++tn) b_n[tn] = ldfrag(Wm, (kc + 1) * 8 + tn, lane);
            }
            #pragma unroll
            for (int tn = 0; tn < 8; ++tn)
                macc[tn] = __builtin_amdgcn_mfma_f32_16x16x32_bf16(a_c, b_c[tn], macc[tn], 0, 0, 0);
        }
    }

    // ---------- phase 2: x_ji GEMM, hin = x_ji + m ----------
    float hin[8][4];
    {
        short8 af[4];
        #pragma unroll
        for (int kc = 0; kc < 4; ++kc)
            af[kc] = *(const short8*)(Xb + (size_t)(row0 + llo) * HD + kc * 32 + lhi * 8);
        floatx4 acc[8]; ZERO_ACC8(acc);
        #pragma unroll
        for (int kc = 0; kc < 4; ++kc) {
            short8 bq[8];
            #pragma unroll
            for (int tn = 0; tn < 8; ++tn) bq[tn] = ldfrag(Wji, kc * 8 + tn, lane);
            #pragma unroll
            for (int tn = 0; tn < 8; ++tn)
                acc[tn] = __builtin_amdgcn_mfma_f32_16x16x32_bf16(af[kc], bq[tn], acc[tn], 0, 0, 0);
        }
        #pragma unroll
        for (int tn = 0; tn < 8; ++tn) {
            int col = tn * 16 + llo;
            #pragma unroll
            for (int q = 0; q < 4; ++q)
                hin[tn][q] = siluf(acc[tn][q] + bjiS[col]) + macc[tn][q];
        }
    }

    // ---------- phase 3: mega chain ----------
    float cur[8][4], trunk[8][4];
    #pragma unroll
    for (int tn = 0; tn < 8; ++tn)
        #pragma unroll
        for (int q = 0; q < 4; ++q) cur[tn][q] = hin[tn][q];

    for (int s = 0; s < 7; ++s) {
        #pragma unroll
        for (int tn = 0; tn < 8; ++tn)
            #pragma unroll
            for (int q = 0; q < 4; ++q)
                Tw[lhi * 4 + q][tn * 16 + llo] = f2us(cur[tn][q]);
        wave_lds_fence();

        const ushort_t* W = Wc + (size_t)s * MSZ;
        floatx4 acc[8]; ZERO_ACC8(acc);
        #pragma unroll
        for (int kc = 0; kc < 4; ++kc) {
            short8 a8 = *(const short8*)&Tw[llo][kc * 32 + lhi * 8];
            short8 bq[8];
            #pragma unroll
            for (int tn = 0; tn < 8; ++tn) bq[tn] = ldfrag(W, kc * 8 + tn, lane);
            #pragma unroll
            for (int tn = 0; tn < 8; ++tn)
                acc[tn] = __builtin_amdgcn_mfma_f32_16x16x32_bf16(a8, bq[tn], acc[tn], 0, 0, 0);
        }
        wave_lds_fence();

        #pragma unroll
        for (int tn = 0; tn < 8; ++tn) {
            int col = tn * 16 + llo;
            #pragma unroll
            for (int q = 0; q < 4; ++q) {
                int grow = row0 + lhi * 4 + q;
                float t = siluf(acc[tn][q] + bs[s * HD + col]);
                if (s == 0)      cur[tn][q] = t;
                else if (s == 1) cur[tn][q] = t + hin[tn][q];
                else if (s == 2) { cur[tn][q] = t + X[(size_t)grow * HD + col]; trunk[tn][q] = cur[tn][q]; }
                else if (s == 3 || s == 5) cur[tn][q] = t;
                else { cur[tn][q] = t + trunk[tn][q]; trunk[tn][q] = cur[tn][q]; }
            }
        }
    }
    #pragma unroll
    for (int tn = 0; tn < 8; ++tn) {
        int col = tn * 16 + llo;
        #pragma unroll
        for (int q = 0; q < 4; ++q) {
            int grow = row0 + lhi * 4 + q;
            if (grow >= c1) continue;
            size_t o = (size_t)grow * HD + col;
            X[o] = cur[tn][q];
            Xbo[o] = f2us(cur[tn][q]);
        }
    }
}

// ---------------------------------------------------------------------------
// Atom-side: wide CSR gather + small chain (Wl in fragment order)
// ---------------------------------------------------------------------------
__global__ __launch_bounds__(256)
void gatherT_k(const ushort_t* __restrict__ Xb, const float* __restrict__ rbf,
               const float* __restrict__ Wr6, const int* __restrict__ eoffs,
               const int* __restrict__ esorted, ushort_t* __restrict__ TA, int M)
{
    __shared__ float W6s[NRR * HD];
    const int tid = threadIdx.x, wave = tid >> 6, lane = tid & 63;
    for (int i = tid; i < NRR * HD; i += 256) W6s[i] = Wr6[i];
    __syncthreads();
    int a0 = (blockIdx.x * 4 + wave) * 2;
    #pragma unroll
    for (int s = 0; s < 2; ++s) {
        int a = a0 + s;
        if (a >= M) return;
        float acc0 = 0.f, acc1 = 0.f;
        int k1 = eoffs[a + 1];
        for (int k = eoffs[a]; k < k1; ++k) {
            int e = esorted[k];
            float r6[NRR];
            #pragma unroll
            for (int r = 0; r < NRR; ++r) r6[r] = rbf[(size_t)e * NRR + r];
            float rp0 = 0.f, rp1 = 0.f;
            #pragma unroll
            for (int r = 0; r < NRR; ++r) {
                rp0 += r6[r] * W6s[r * HD + lane];
                rp1 += r6[r] * W6s[r * HD + 64 + lane];
            }
            acc0 += rp0 * us2f(Xb[(size_t)e * HD + lane]);
            acc1 += rp1 * us2f(Xb[(size_t)e * HD + 64 + lane]);
        }
        TA[(size_t)a * HD + lane] = f2us(acc0);
        TA[(size_t)a * HD + 64 + lane] = f2us(acc1);
    }
}

__global__ __launch_bounds__(256, 3)
void atomchain_w(const ushort_t* __restrict__ TA, const ushort_t* __restrict__ Wl,
                 const float* __restrict__ bl, const float* __restrict__ wout,
                 float* __restrict__ P, int M)
{
    __shared__ float blS[3 * HD];
    __shared__ float woS[HD];
    __shared__ ushort_t T[4][16][136];
    const int tid = threadIdx.x, wave = tid >> 6, lane = tid & 63;
    const int llo = lane & 15, lhi = lane >> 4;
    for (int i = tid; i < 3 * HD; i += 256) blS[i] = bl[i];
    if (tid < HD) woS[tid] = wout[tid];
    __syncthreads();
    const int row0 = (blockIdx.x * 4 + wave) * 16;
    if (row0 >= M) return;
    ushort_t (*Tw)[136] = T[wave];

    #pragma unroll
    for (int s = 0; s < 3; ++s) {
        short8 af[4];
        if (s == 0) {
            #pragma unroll
            for (int kc = 0; kc < 4; ++kc)
                af[kc] = *(const short8*)(TA + (size_t)(row0 + llo) * HD + kc * 32 + lhi * 8);
        } else {
            #pragma unroll
            for (int kc = 0; kc < 4; ++kc)
                af[kc] = *(const short8*)&Tw[llo][kc * 32 + lhi * 8];
        }
        const ushort_t* W = Wl + (size_t)s * MSZ;
        floatx4 acc[8]; ZERO_ACC8(acc);
        #pragma unroll
        for (int kc = 0; kc < 4; ++kc) {
            short8 bq[8];
            #pragma unroll
            for (int tn = 0; tn < 8; ++tn) bq[tn] = ldfrag(W, kc * 8 + tn, lane);
            #pragma unroll
            for (int tn = 0; tn < 8; ++tn)
                acc[tn] = __builtin_amdgcn_mfma_f32_16x16x32_bf16(af[kc], bq[tn], acc[tn], 0, 0, 0);
        }
        if (s < 2) {
            wave_lds_fence();
            #pragma unroll
            for (int tn = 0; tn < 8; ++tn) {
                int col = tn * 16 + llo;
                #pragma unroll
                for (int q = 0; q < 4; ++q)
                    Tw[lhi * 4 + q][col] = f2us(siluf(acc[tn][q] + blS[s * HD + col]));
            }
            wave_lds_fence();
        } else {
            #pragma unroll
            for (int q = 0; q < 4; ++q) {
                float v = 0.f;
                #pragma unroll
                for (int tn = 0; tn < 8; ++tn) {
                    int col = tn * 16 + llo;
                    v += siluf(acc[tn][q] + blS[2 * HD + col]) * woS[col];
                }
                v += __shfl_xor(v, 1); v += __shfl_xor(v, 2);
                v += __shfl_xor(v, 4); v += __shfl_xor(v, 8);
                int a = row0 + lhi * 4 + q;
                if (llo == 0 && a < M) P[a] += v;
            }
        }
    }
}

// ---------------- small kernels ----------------
__global__ void emb_lin_k(const float* __restrict__ emb_table, const float* __restrict__ emb_w,
                          float* __restrict__ A0, float* __restrict__ A1)
{
    __shared__ float er[HD];
    int a = blockIdx.x, h = threadIdx.x;
    er[h] = emb_table[a * HD + h];
    __syncthreads();
    float acc0 = 0.f, acc1 = 0.f;
    #pragma unroll 8
    for (int l = 0; l < HD; ++l) {
        float e = er[l];
        acc0 += e * emb_w[l * HD + h];
        acc1 += e * emb_w[(HD + l) * HD + h];
    }
    A0[a * HD + h] = acc0;
    A1[a * HD + h] = acc1;
}

__global__ void sbf_proj_s(const float* __restrict__ sbf, const float* __restrict__ W,
                           const int* __restrict__ tpos, ushort_t* __restrict__ sps)
{
    __shared__ float Ws[NSNR * NBB];
    for (int s = threadIdx.x; s < NSNR * NBB; s += 256) Ws[s] = W[s];
    __syncthreads();
    int t = blockIdx.x * 256 + threadIdx.x;
    if (t >= NTRIP) return;
    float acc[NBB];
    #pragma unroll
    for (int n = 0; n < NBB; ++n) acc[n] = 0.f;
    #pragma unroll
    for (int r = 0; r < NSNR; ++r) {
        float v = sbf[(size_t)t * NSNR + r];
        #pragma unroll
        for (int n = 0; n < NBB; ++n) acc[n] += v * Ws[r * NBB + n];
    }
    int p = tpos[t];
    ushort_t* o = sps + (size_t)p * NBB;
    #pragma unroll
    for (int n = 0; n < NBB; ++n) o[n] = f2us(acc[n]);
}

__global__ void graph_sum_k(const float* __restrict__ P, const int* __restrict__ batch,
                            float* __restrict__ outg)
{
    int a = blockIdx.x * 256 + threadIdx.x;
    if (a >= NATOMS) return;
    atomicAdd(&outg[batch[a]], P[a]);
}

// ---------------------------------------------------------------------------
extern "C" void kernel_launch(void* const* d_in, const int* in_sizes, int n_in,
                              void* d_out, int out_size, void* d_ws, size_t ws_size,
                              hipStream_t stream)
{
    const int*   z         = (const int*)  d_in[0];
    const float* rbf       = (const float*)d_in[1];
    const float* sbf       = (const float*)d_in[2];
    const int*   ii        = (const int*)  d_in[3];
    const int*   jj        = (const int*)  d_in[4];
    const int*   idx_kj    = (const int*)  d_in[5];
    const int*   idx_ji    = (const int*)  d_in[6];
    const int*   batch     = (const int*)  d_in[7];
    const float* emb_table = (const float*)d_in[8];
    const float* emb_rbf_w = (const float*)d_in[9];
    const float* emb_rbf_b = (const float*)d_in[10];
    const float* emb_w     = (const float*)d_in[11];
    const float* emb_b     = (const float*)d_in[12];
    const float* int_rbf_w = (const float*)d_in[13];
    const float* int_sbf_w = (const float*)d_in[14];
    const float* int_kj_w  = (const float*)d_in[15];
    const float* int_kj_b  = (const float*)d_in[16];
    const float* int_ji_w  = (const float*)d_in[17];
    const float* int_ji_b  = (const float*)d_in[18];
    const float* int_W     = (const float*)d_in[19];
    const float* int_bef_w = (const float*)d_in[20];
    const float* int_bef_b = (const float*)d_in[21];
    const float* int_lin_w = (const float*)d_in[22];
    const float* int_lin_b = (const float*)d_in[23];
    const float* int_aft_w = (const float*)d_in[24];
    const float* int_aft_b = (const float*)d_in[25];
    const float* out_rbf_w = (const float*)d_in[26];
    const float* out_lins_w= (const float*)d_in[27];
    const float* out_lins_b= (const float*)d_in[28];
    const float* out_w     = (const float*)d_in[29];
    float* d_outf          = (float*)d_out;

    const size_t EH = (size_t)NEDGES * HD;
    const int OFF_EMB = 0, OFF_KJ = 1, OFF_JI = 7, OFF_CHAIN = 13, OFF_OUTL = 55;

    char* base = (char*)d_ws;
    auto take = [&](size_t bytes) { char* p = base; base += (bytes + 255) & ~(size_t)255; return p; };
    float* bufA    = (float*)take(EH * 4);                     // X fp32 trunk
    ushort_t* Xb   = (ushort_t*)take(EH * 2);                  // X bf16 shadow
    ushort_t* Cb   = (ushort_t*)take(EH * 2);                  // x_kj bf16
    ushort_t* sps  = (ushort_t*)take((size_t)NTRIP * NBB * 2); // sp, tsorted order
    ushort_t* TA   = (ushort_t*)take((size_t)NATOMS * HD * 2);
    float* P_atom  = (float*)take((size_t)NATOMS * 4);
    float* A0      = (float*)take(95 * HD * 4);
    float* A1      = (float*)take(95 * HD * 4);
    float* bc      = (float*)take((size_t)NBLKS * 7 * HD * 4);
    int*   counts  = (int*)  take((size_t)(NEDGES + 1) * 4);
    int*   bsum    = (int*)  take(1024 * 4);
    int*   toffs   = (int*)  take((size_t)(NEDGES + 1) * 4);
    int*   eoffs   = (int*)  take((size_t)(NATOMS + 1) * 4);
    int*   tsorted = (int*)  take((size_t)NTRIP * 4);
    int*   esorted = (int*)  take((size_t)NEDGES * 4);
    int*   tpos    = (int*)  take((size_t)NTRIP * 4);
    int*   ekjs    = (int*)  take((size_t)NTRIP * 4);
    ushort_t* w128 = (ushort_t*)take((size_t)76 * MSZ * 2);
    ushort_t* wM   = (ushort_t*)take((size_t)NBLKS * HD * 1024 * 2);
    size_t fixed   = (size_t)(base - (char*)d_ws);
    ushort_t* G    = (ushort_t*)base;

    // adaptive chunking of G (chunk rows multiple of 16)
    int nch = 8;
    for (int c = 1; c <= 8; ++c) {
        int ch = ((NEDGES + c - 1) / c + 15) & ~15;
        size_t gb = (size_t)ch * 1024 * 2;
        if (fixed + gb <= ws_size) { nch = c; break; }
    }
    const int CH = ((NEDGES + nch - 1) / nch + 15) & ~15;

    auto zero = [&](float* p, size_t n) {
        zerof_k<<<((int)n + 255) / 256, 256, 0, stream>>>(p, (int)n);
    };

    // ---------------- weight prep ----------------
    transp128_k<<< 1, 256, 0, stream>>>(emb_w + 2 * MSZ, w128 + (size_t)OFF_EMB * MSZ);  // classic
    transp128s_k<<< 6, 256, 0, stream>>>(int_kj_w,   w128 + (size_t)OFF_KJ  * MSZ);
    transp128s_k<<< 6, 256, 0, stream>>>(int_ji_w,   w128 + (size_t)OFF_JI  * MSZ);
    for (int b = 0; b < NBLKS; ++b) {
        transp128s_k<<<2, 256, 0, stream>>>(int_bef_w + (size_t)b * 2 * MSZ,
                                            w128 + (size_t)(OFF_CHAIN + b * 7) * MSZ);
        transp128s_k<<<1, 256, 0, stream>>>(int_lin_w + (size_t)b * MSZ,
                                            w128 + (size_t)(OFF_CHAIN + b * 7 + 2) * MSZ);
        transp128s_k<<<4, 256, 0, stream>>>(int_aft_w + (size_t)b * 4 * MSZ,
                                            w128 + (size_t)(OFF_CHAIN + b * 7 + 3) * MSZ);
    }
    transp128s_k<<<21, 256, 0, stream>>>(out_lins_w, w128 + (size_t)OFF_OUTL * MSZ);
    castWMs_k<<<(NBLKS * HD * 1024 + 255) / 256, 256, 0, stream>>>(int_W, wM, NBLKS * HD * 1024);
    pack_bc_k<<<NBLKS, 256, 0, stream>>>(int_bef_b, int_lin_b, int_aft_b, bc);

    // ---------------- CSR builds ----------------
    {
        zeroi_k<<<(NEDGES + 255) / 256, 256, 0, stream>>>(counts, NEDGES);
        hist_k<<<(NTRIP + 255) / 256, 256, 0, stream>>>(idx_ji, NTRIP, counts);
        int nb = (NEDGES + 255) / 256;
        blksum_k<<<nb, 256, 0, stream>>>(counts, NEDGES, bsum);
        scanb_k<<<1, 1024, 0, stream>>>(bsum, nb);
        scanfin_k<<<nb, 256, 0, stream>>>(counts, NEDGES, bsum, toffs);
        zeroi_k<<<(NEDGES + 255) / 256, 256, 0, stream>>>(counts, NEDGES);
        fill_k<<<(NTRIP + 255) / 256, 256, 0, stream>>>(idx_ji, NTRIP, toffs, counts, tsorted);
        invperm_k<<<(NTRIP + 255) / 256, 256, 0, stream>>>(tsorted, idx_kj, tpos, ekjs, NTRIP);
    }
    {
        zeroi_k<<<(NATOMS + 255) / 256, 256, 0, stream>>>(counts, NATOMS);
        hist_k<<<(NEDGES + 255) / 256, 256, 0, stream>>>(ii, NEDGES, counts);
        int nb = (NATOMS + 255) / 256;
        blksum_k<<<nb, 256, 0, stream>>>(counts, NATOMS, bsum);
        scanb_k<<<1, 1024, 0, stream>>>(bsum, nb);
        scanfin_k<<<nb, 256, 0, stream>>>(counts, NATOMS, bsum, eoffs);
        zeroi_k<<<(NATOMS + 255) / 256, 256, 0, stream>>>(counts, NATOMS);
        fill_k<<<(NEDGES + 255) / 256, 256, 0, stream>>>(ii, NEDGES, eoffs, counts, esorted);
    }

    const int EGRID = (NEDGES + 127) / 128;
    const int EW    = (NEDGES / 16 + 3) / 4;
    const int AW    = (NATOMS / 16 + 3) / 4;
    const int GW    = (NATOMS / 2 + 3) / 4;
    auto out_block = [&](int k) {
        gatherT_k<<<GW, 256, 0, stream>>>(
            Xb, rbf, out_rbf_w + (size_t)k * NRR * HD, eoffs, esorted, TA, NATOMS);
        atomchain_w<<<AW, 256, 0, stream>>>(
            TA, w128 + (size_t)(OFF_OUTL + 3 * k) * MSZ,
            out_lins_b + (size_t)k * 3 * HD, out_w + (size_t)k * HD, P_atom, NATOMS);
    };

    // ---------------- Embedding ----------------
    emb_lin_k<<<95, HD, 0, stream>>>(emb_table, emb_w, A0, A1);
    emb_chain_k<<<EGRID, 256, 0, stream>>>(
        rbf, emb_rbf_w, emb_rbf_b, w128 + (size_t)OFF_EMB * MSZ,
        A0, A1, emb_b, z, ii, jj, bufA, Xb, NEDGES);

    zero(P_atom, NATOMS);
    out_block(0);

    // ---------------- Interaction blocks ----------------
    for (int b = 0; b < NBLKS; ++b) {
        sbf_proj_s<<<(NTRIP + 255) / 256, 256, 0, stream>>>(
            sbf, int_sbf_w + (size_t)b * NSNR * NBB, tpos, sps);

        kjcb_w<<<EW, 256, 0, stream>>>(
            Xb, w128 + (size_t)(OFF_KJ + b) * MSZ, int_kj_b + (size_t)b * HD,
            rbf, int_rbf_w + (size_t)b * NRR * HD, Cb, NEDGES);

        for (int c = 0; c < nch; ++c) {
            int c0 = c * CH;
            int c1 = (c0 + CH < NEDGES) ? c0 + CH : NEDGES;
            if (c0 >= c1) break;
            int ne = c1 - c0;
            trip_accum_k<<<(ne + 1) / 2, 256, 0, stream>>>(
                sps, Cb, toffs, ekjs, G, c0, c1);
            int gw = ((ne + 15) / 16 + 3) / 4;
            megaK_w<<<gw, 256, 0, stream>>>(
                G, Xb, wM + (size_t)b * HD * 1024,
                w128 + (size_t)(OFF_JI + b) * MSZ, int_ji_b + (size_t)b * HD,
                w128 + (size_t)(OFF_CHAIN + b * 7) * MSZ, bc + (size_t)b * 7 * HD,
                bufA, Xb, c0, c1);
        }

        out_block(b + 1);
    }

    // ---------------- Final graph reduction ----------------
    zero(d_outf, NGRAPH);
    graph_sum_k<<<(NATOMS + 255) / 256, 256, 0, stream>>>(P_atom, batch, d_outf);
}

// Round 12
// 3965.315 us; speedup vs baseline: 1.7962x; 1.0052x over previous
//
#include <hip/hip_runtime.h>
#include <cstdint>
#include <cstddef>

typedef unsigned short ushort_t;
typedef unsigned int uint_t;

#define NATOMS 8000
#define NEDGES 100000
#define NTRIP  500000
#define NGRAPH 64
#define HD     128
#define NRR    6
#define NSNR   42
#define NBB    8
#define NBLKS  6
#define MSZ    16384

using short8   = __attribute__((ext_vector_type(8))) short;
using ushort8v = __attribute__((ext_vector_type(8))) unsigned short;
using floatx4  = __attribute__((ext_vector_type(4))) float;

__device__ __forceinline__ float siluf(float x){ return x / (1.f + __expf(-x)); }
__device__ __forceinline__ ushort_t f2us(float f){
    uint_t u = __builtin_bit_cast(uint_t, f);
    u = (u + 0x7FFFu + ((u >> 16) & 1u)) >> 16;
    return (ushort_t)u;
}
__device__ __forceinline__ float us2f(ushort_t s){
    uint_t u = ((uint_t)s) << 16;
    return __builtin_bit_cast(float, u);
}
__device__ __forceinline__ void wave_lds_fence(){
    asm volatile("s_waitcnt lgkmcnt(0)" ::: "memory");
}
__device__ __forceinline__ short8 ldfrag(const ushort_t* W, int frag, int lane){
    return *(const short8*)(W + ((size_t)(frag * 64 + lane) << 3));
}

__global__ void zerof_k(float* __restrict__ p, int n){ int i=blockIdx.x*256+threadIdx.x; if(i<n) p[i]=0.f; }
__global__ void zeroi_k(int* __restrict__ p, int n){ int i=blockIdx.x*256+threadIdx.x; if(i<n) p[i]=0; }

// ---------------- weight prep ----------------
__global__ __launch_bounds__(256)
void transp128_k(const float* __restrict__ src, ushort_t* __restrict__ dst)
{
    __shared__ ushort_t L[128][130];
    int m = blockIdx.x;
    const float* S = src + (size_t)m * MSZ;
    ushort_t* D = dst + (size_t)m * MSZ;
    int tid = threadIdx.x;
    #pragma unroll
    for (int p = 0; p < 64; ++p) {
        int idx = p * 256 + tid;
        int k = idx >> 7, n = idx & 127;
        L[k][n] = f2us(S[idx]);
    }
    __syncthreads();
    #pragma unroll
    for (int p = 0; p < 64; ++p) {
        int idx = p * 256 + tid;
        int n = idx >> 7, k = idx & 127;
        D[idx] = L[k][n];
    }
}

// fragment order (K=128)
__global__ __launch_bounds__(256)
void transp128s_k(const float* __restrict__ src, ushort_t* __restrict__ dst)
{
    int m = blockIdx.x;
    const float* S = src + (size_t)m * MSZ;
    ushort_t* D = dst + (size_t)m * MSZ;
    int tid = threadIdx.x;
    #pragma unroll
    for (int p = 0; p < 64; ++p) {
        int idx = p * 256 + tid;
        int k = idx >> 7, n = idx & 127;
        size_t d = ((size_t)(((k >> 5) * 8 + (n >> 4)) * 64 + ((k >> 3) & 3) * 16 + (n & 15)) << 3)
                   + (k & 7);
        D[d] = f2us(S[idx]);
    }
}

// int_W -> fragment order (K=1024)
__global__ void castWMs_k(const float* __restrict__ src, ushort_t* __restrict__ dst, int n)
{
    int i = blockIdx.x * 256 + threadIdx.x;
    if (i >= n) return;
    int b = i >> 17;
    int r = i & 131071;
    int nn = r >> 10, k = r & 1023;
    size_t d = (size_t)b * 131072
             + ((size_t)(((k >> 5) * 8 + (nn >> 4)) * 64 + ((k >> 3) & 3) * 16 + (nn & 15)) << 3)
             + (k & 7);
    dst[d] = f2us(src[i]);
}

__global__ void pack_bc_k(const float* __restrict__ bef, const float* __restrict__ lin,
                          const float* __restrict__ aft, float* __restrict__ bc)
{
    int b = blockIdx.x;
    for (int i = threadIdx.x; i < 7 * HD; i += 256) {
        int s = i >> 7, h = i & 127;
        float v;
        if (s < 2)      v = bef[(size_t)(b * 2 + s) * HD + h];
        else if (s == 2) v = lin[(size_t)b * HD + h];
        else             v = aft[(size_t)(b * 4 + (s - 3)) * HD + h];
        bc[(size_t)b * 7 * HD + i] = v;
    }
}

// ---------------- CSR build ----------------
__global__ void hist_k(const int* __restrict__ idx, int n, int* __restrict__ cnt)
{
    int i = blockIdx.x * 256 + threadIdx.x;
    if (i < n) atomicAdd(&cnt[idx[i]], 1);
}
__global__ void blksum_k(const int* __restrict__ c, int n, int* __restrict__ bs)
{
    int i = blockIdx.x * 256 + threadIdx.x;
    int v = (i < n) ? c[i] : 0;
    #pragma unroll
    for (int off = 32; off; off >>= 1) v += __shfl_down(v, off);
    __shared__ int sh[4];
    if ((threadIdx.x & 63) == 0) sh[threadIdx.x >> 6] = v;
    __syncthreads();
    if (threadIdx.x == 0) bs[blockIdx.x] = sh[0] + sh[1] + sh[2] + sh[3];
}
__global__ void scanb_k(int* __restrict__ bs, int nb)
{
    __shared__ int sh[1024];
    int t = threadIdx.x;
    int v = (t < nb) ? bs[t] : 0;
    sh[t] = v; __syncthreads();
    for (int off = 1; off < 1024; off <<= 1) {
        int u = (t >= off) ? sh[t - off] : 0;
        __syncthreads();
        sh[t] += u;
        __syncthreads();
    }
    if (t < nb) bs[t] = sh[t] - v;
}
__global__ void scanfin_k(const int* __restrict__ c, int n, const int* __restrict__ bs,
                          int* __restrict__ offs)
{
    __shared__ int sh[256];
    int t = threadIdx.x;
    int i = blockIdx.x * 256 + t;
    int v = (i < n) ? c[i] : 0;
    sh[t] = v; __syncthreads();
    for (int off = 1; off < 256; off <<= 1) {
        int u = (t >= off) ? sh[t - off] : 0;
        __syncthreads();
        sh[t] += u;
        __syncthreads();
    }
    if (i < n)  offs[i] = bs[blockIdx.x] + sh[t] - v;
    if (i == n - 1) offs[n] = bs[blockIdx.x] + sh[t];
}
__global__ void fill_k(const int* __restrict__ idx, int n, const int* __restrict__ offs,
                       int* __restrict__ cur, int* __restrict__ sorted)
{
    int i = blockIdx.x * 256 + threadIdx.x;
    if (i >= n) return;
    int e = idx[i];
    int p = offs[e] + atomicAdd(&cur[e], 1);
    sorted[p] = i;
}
__global__ void invperm_k(const int* __restrict__ tsorted, const int* __restrict__ idx_kj,
                          int* __restrict__ tpos, int* __restrict__ ekjs, int n)
{
    int k = blockIdx.x * 256 + threadIdx.x;
    if (k >= n) return;
    int t = tsorted[k];
    tpos[t] = k;
    ekjs[k] = idx_kj[t];
}

// ---------------------------------------------------------------------------
// Legacy block helpers (emb_chain only)
// ---------------------------------------------------------------------------
__device__ __forceinline__ void load_bh(const ushort_t* Bt, int kh, int tid, ushort8v r[4])
{
    #pragma unroll
    for (int p = 0; p < 4; ++p) {
        int c = p * 256 + tid;
        int n = c >> 3, c8 = c & 7;
        r[p] = *(const ushort8v*)(Bt + (size_t)n * 128 + kh * 64 + c8 * 8);
    }
}
__device__ __forceinline__ void store_bh(ushort8v r[4], ushort_t (*Bl)[72], int tid)
{
    #pragma unroll
    for (int p = 0; p < 4; ++p) {
        int c = p * 256 + tid;
        *(ushort8v*)&Bl[c >> 3][(c & 7) * 8] = r[p];
    }
}
__device__ __forceinline__ void mfma_kh(ushort_t (*Al)[136], ushort_t (*Bl)[72],
                                        floatx4 acc[4][4], int kh,
                                        int wr, int wc, int lhi, int llo)
{
    #pragma unroll
    for (int ks = 0; ks < 2; ++ks) {
        int kk = ks * 32 + lhi * 8;
        short8 af[4], bf[4];
        #pragma unroll
        for (int tm = 0; tm < 4; ++tm)
            af[tm] = *(const short8*)&Al[wr * 64 + tm * 16 + llo][kh * 64 + kk];
        #pragma unroll
        for (int tn = 0; tn < 4; ++tn)
            bf[tn] = *(const short8*)&Bl[wc * 64 + tn * 16 + llo][kk];
        #pragma unroll
        for (int tm = 0; tm < 4; ++tm)
            #pragma unroll
            for (int tn = 0; tn < 4; ++tn)
                acc[tm][tn] = __builtin_amdgcn_mfma_f32_16x16x32_bf16(
                    af[tm], bf[tn], acc[tm][tn], 0, 0, 0);
    }
}
#define ZERO_ACC4(acc) { _Pragma("unroll") for (int a_=0;a_<4;++a_) _Pragma("unroll") \
    for (int b_=0;b_<4;++b_) _Pragma("unroll") for (int q_=0;q_<4;++q_) acc[a_][b_][q_]=0.f; }
#define ZERO_ACC8(acc) { _Pragma("unroll") for (int t_=0;t_<8;++t_) { acc[t_][0]=0.f; acc[t_][1]=0.f; acc[t_][2]=0.f; acc[t_][3]=0.f; } }

// ---------------------------------------------------------------------------
// Embedding chain (block-tiled, classic weight layout)
// ---------------------------------------------------------------------------
__global__ __launch_bounds__(256)
void emb_chain_k(const float* __restrict__ rbf, const float* __restrict__ W6g,
                 const float* __restrict__ b6g, const ushort_t* __restrict__ Wemb3,
                 const float* __restrict__ A0, const float* __restrict__ A1,
                 const float* __restrict__ emb_b, const int* __restrict__ z,
                 const int* __restrict__ ii, const int* __restrict__ jj,
                 float* __restrict__ X, ushort_t* __restrict__ Xb, int M)
{
    __shared__ ushort_t Al[128][136];
    __shared__ ushort_t Bl[128][72];
    __shared__ float W6[NRR * HD];
    __shared__ float b6s[HD];
    const int tid = threadIdx.x, row0 = blockIdx.x * 128;
    const int wave = tid >> 6, lane = tid & 63;
    const int wr = wave >> 1, wc_ = wave & 1, lhi = lane >> 4, llo = lane & 15;

    for (int i = tid; i < NRR * HD; i += 256) W6[i] = W6g[i];
    if (tid < HD) b6s[tid] = b6g[tid];
    ushort8v r0[4], r1[4];
    load_bh(Wemb3, 0, tid, r0); load_bh(Wemb3, 1, tid, r1);
    __syncthreads();

    {
        int e_l = tid >> 1, half = tid & 1;
        int grow = row0 + e_l; if (grow >= M) grow = M - 1;
        float r6[NRR];
        #pragma unroll
        for (int r = 0; r < NRR; ++r) r6[r] = rbf[(size_t)grow * NRR + r];
        #pragma unroll 8
        for (int hh = 0; hh < 64; ++hh) {
            int h = half * 64 + hh;
            float a = b6s[h];
            #pragma unroll
            for (int r = 0; r < NRR; ++r) a += r6[r] * W6[r * HD + h];
            Al[e_l][h] = f2us(siluf(a));
        }
    }
    __syncthreads();

    floatx4 acc[4][4]; ZERO_ACC4(acc);
    store_bh(r0, Bl, tid); __syncthreads();
    mfma_kh(Al, Bl, acc, 0, wr, wc_, lhi, llo);
    __syncthreads();
    store_bh(r1, Bl, tid); __syncthreads();
    mfma_kh(Al, Bl, acc, 1, wr, wc_, lhi, llo);

    #pragma unroll
    for (int tm = 0; tm < 4; ++tm)
        #pragma unroll
        for (int q = 0; q < 4; ++q) {
            int grow = row0 + wr * 64 + tm * 16 + lhi * 4 + q;
            if (grow >= M) continue;
            int zi = z[ii[grow]], zj = z[jj[grow]];
            #pragma unroll
            for (int tn = 0; tn < 4; ++tn) {
                int coll = wc_ * 64 + tn * 16 + llo;
                float t = acc[tm][tn][q] + A0[zi * HD + coll] + A1[zj * HD + coll] + emb_b[coll];
                float v = siluf(t);
                size_t o = (size_t)grow * HD + coll;
                X[o] = v; Xb[o] = f2us(v);
            }
        }
}

// ---------------------------------------------------------------------------
// kjcb: Cb = bf16( silu(x@Wkj+b) * rbfp )   (Wkj in fragment order)
// ---------------------------------------------------------------------------
__global__ __launch_bounds__(256, 3)
void kjcb_w(const ushort_t* __restrict__ Xb, const ushort_t* __restrict__ Wkj,
            const float* __restrict__ bkj, const float* __restrict__ rbf,
            const float* __restrict__ Wr6, ushort_t* __restrict__ Cb, int M)
{
    __shared__ float W6s[NRR * HD];
    __shared__ float bkjS[HD];
    const int tid = threadIdx.x, wave = tid >> 6, lane = tid & 63;
    const int llo = lane & 15, lhi = lane >> 4;
    for (int i = tid; i < NRR * HD; i += 256) W6s[i] = Wr6[i];
    if (tid < HD) bkjS[tid] = bkj[tid];
    __syncthreads();
    const int row0 = (blockIdx.x * 4 + wave) * 16;
    if (row0 >= M) return;

    short8 af[4];
    #pragma unroll
    for (int kc = 0; kc < 4; ++kc)
        af[kc] = *(const short8*)(Xb + (size_t)(row0 + llo) * HD + kc * 32 + lhi * 8);

    float rb[4][NRR];
    {
        const float* rp = rbf + (size_t)(row0 + lhi * 4) * NRR;
        #pragma unroll
        for (int q = 0; q < 4; ++q)
            #pragma unroll
            for (int r = 0; r < NRR; ++r) rb[q][r] = rp[q * NRR + r];
    }

    floatx4 acc[8]; ZERO_ACC8(acc);
    #pragma unroll
    for (int kc = 0; kc < 4; ++kc) {
        short8 bq[8];
        #pragma unroll
        for (int tn = 0; tn < 8; ++tn) bq[tn] = ldfrag(Wkj, kc * 8 + tn, lane);
        #pragma unroll
        for (int tn = 0; tn < 8; ++tn)
            acc[tn] = __builtin_amdgcn_mfma_f32_16x16x32_bf16(af[kc], bq[tn], acc[tn], 0, 0, 0);
    }
    #pragma unroll
    for (int tn = 0; tn < 8; ++tn) {
        int col = tn * 16 + llo;
        #pragma unroll
        for (int q = 0; q < 4; ++q) {
            int grow = row0 + lhi * 4 + q;
            if (grow >= M) continue;
            float rpv = 0.f;
            #pragma unroll
            for (int r = 0; r < NRR; ++r) rpv += rb[q][r] * W6s[r * HD + col];
            Cb[(size_t)grow * HD + col] = f2us(siluf(acc[tn][q] + bkjS[col]) * rpv);
        }
    }
}

// ---------------------------------------------------------------------------
// Triplet accumulate (software-pipelined): writes G in A-fragment order.
// ---------------------------------------------------------------------------
__global__ __launch_bounds__(256)
void trip_accum_k(const ushort_t* __restrict__ sps, const ushort_t* __restrict__ Cb,
                  const int* __restrict__ toffs, const int* __restrict__ ekjs,
                  ushort_t* __restrict__ G, int c0, int c1)
{
    int e = c0 + blockIdx.x * 2 + (threadIdx.x >> 7);
    if (e >= c1) return;
    int h = threadIdx.x & 127;
    float acc[NBB];
    #pragma unroll
    for (int j = 0; j < NBB; ++j) acc[j] = 0.f;
    int k0 = toffs[e], k1 = toffs[e + 1];
    if (k0 < k1) {
        ushort_t  c_n = Cb[(size_t)ekjs[k0] * HD + h];
        ushort8v  s_n = *(const ushort8v*)(sps + (size_t)k0 * NBB);
        for (int k = k0; k < k1; ++k) {
            ushort_t  c_c = c_n;
            ushort8v  s_c = s_n;
            if (k + 1 < k1) {
                c_n = Cb[(size_t)ekjs[k + 1] * HD + h];
                s_n = *(const ushort8v*)(sps + (size_t)(k + 1) * NBB);
            }
            float v = us2f(c_c);
            #pragma unroll
            for (int j = 0; j < NBB; ++j) acc[j] += us2f(s_c[j]) * v;
        }
    }
    int rel = e - c0;
    int tile = rel >> 4, el = rel & 15;
    int lhi = (h >> 3) & 3, j8 = h & 7, hc = h >> 5;
    #pragma unroll
    for (int j = 0; j < NBB; ++j) {
        size_t d = ((size_t)((tile * 32 + j * 4 + hc) * 64 + lhi * 16 + el) << 3) + j8;
        G[d] = f2us(acc[j]);
    }
}

// ---------------------------------------------------------------------------
// megaK: per wave 16 edge rows; hin spilled to wave-LDS (bf16) to cut VGPRs.
// ---------------------------------------------------------------------------
__global__ __launch_bounds__(256, 3)
void megaK_w(const ushort_t* __restrict__ G, const ushort_t* __restrict__ Xb,
             const ushort_t* __restrict__ Wm,
             const ushort_t* __restrict__ Wji, const float* __restrict__ bjig,
             const ushort_t* __restrict__ Wc, const float* __restrict__ Bc,
             float* __restrict__ X, ushort_t* __restrict__ Xbo, int c0, int c1)
{
    __shared__ float bjiS[HD];
    __shared__ float bs[7 * HD];
    __shared__ ushort_t T[4][16][136];
    __shared__ ushort_t Hh[4][16][136];
    const int tid = threadIdx.x, wave = tid >> 6, lane = tid & 63;
    const int llo = lane & 15, lhi = lane >> 4;
    if (tid < HD) bjiS[tid] = bjig[tid];
    for (int i = tid; i < 7 * HD; i += 256) bs[i] = Bc[i];
    __syncthreads();
    const int row0 = c0 + (blockIdx.x * 4 + wave) * 16;
    if (row0 >= c1) return;
    ushort_t (*Tw)[136] = T[wave];
    ushort_t (*Hw)[136] = Hh[wave];

    // ---------- phase 1: K=1024 GEMM, register double-buffered ----------
    floatx4 macc[8]; ZERO_ACC8(macc);
    {
        const int tile = (row0 - c0) >> 4;
        const ushort_t* gf = G + ((size_t)(tile * 32) * 64 + lane) * 8;
        short8 a_n = *(const short8*)gf;
        short8 b_n[8];
        #pragma unroll
        for (int tn = 0; tn < 8; ++tn) b_n[tn] = ldfrag(Wm, tn, lane);
        for (int kc = 0; kc < 32; ++kc) {
            short8 a_c = a_n;
            short8 b_c[8];
            #pragma unroll
            for (int tn = 0; tn < 8; ++tn) b_c[tn] = b_n[tn];
            if (kc < 31) {
                a_n = *(const short8*)(gf + (size_t)(kc + 1) * 512);
                #pragma unroll
                for (int tn = 0; tn < 8; ++tn) b_n[tn] = ldfrag(Wm, (kc + 1) * 8 + tn, lane);
            }
            #pragma unroll
            for (int tn = 0; tn < 8; ++tn)
                macc[tn] = __builtin_amdgcn_mfma_f32_16x16x32_bf16(a_c, b_c[tn], macc[tn], 0, 0, 0);
        }
    }

    // ---------- phase 2: x_ji GEMM, hin = x_ji + m (to LDS + cur regs) ----------
    float cur[8][4], trunk[8][4];
    {
        short8 af[4];
        #pragma unroll
        for (int kc = 0; kc < 4; ++kc)
            af[kc] = *(const short8*)(Xb + (size_t)(row0 + llo) * HD + kc * 32 + lhi * 8);
        floatx4 acc[8]; ZERO_ACC8(acc);
        #pragma unroll
        for (int kc = 0; kc < 4; ++kc) {
            short8 bq[8];
            #pragma unroll
            for (int tn = 0; tn < 8; ++tn) bq[tn] = ldfrag(Wji, kc * 8 + tn, lane);
            #pragma unroll
            for (int tn = 0; tn < 8; ++tn)
                acc[tn] = __builtin_amdgcn_mfma_f32_16x16x32_bf16(af[kc], bq[tn], acc[tn], 0, 0, 0);
        }
        #pragma unroll
        for (int tn = 0; tn < 8; ++tn) {
            int col = tn * 16 + llo;
            #pragma unroll
            for (int q = 0; q < 4; ++q) {
                float hv = siluf(acc[tn][q] + bjiS[col]) + macc[tn][q];
                cur[tn][q] = hv;
                Hw[lhi * 4 + q][col] = f2us(hv);
            }
        }
    }

    // ---------- phase 3: mega chain ----------
    for (int s = 0; s < 7; ++s) {
        #pragma unroll
        for (int tn = 0; tn < 8; ++tn)
            #pragma unroll
            for (int q = 0; q < 4; ++q)
                Tw[lhi * 4 + q][tn * 16 + llo] = f2us(cur[tn][q]);
        wave_lds_fence();

        const ushort_t* W = Wc + (size_t)s * MSZ;
        floatx4 acc[8]; ZERO_ACC8(acc);
        #pragma unroll
        for (int kc = 0; kc < 4; ++kc) {
            short8 a8 = *(const short8*)&Tw[llo][kc * 32 + lhi * 8];
            short8 bq[8];
            #pragma unroll
            for (int tn = 0; tn < 8; ++tn) bq[tn] = ldfrag(W, kc * 8 + tn, lane);
            #pragma unroll
            for (int tn = 0; tn < 8; ++tn)
                acc[tn] = __builtin_amdgcn_mfma_f32_16x16x32_bf16(a8, bq[tn], acc[tn], 0, 0, 0);
        }
        wave_lds_fence();

        #pragma unroll
        for (int tn = 0; tn < 8; ++tn) {
            int col = tn * 16 + llo;
            #pragma unroll
            for (int q = 0; q < 4; ++q) {
                int grow = row0 + lhi * 4 + q;
                float t = siluf(acc[tn][q] + bs[s * HD + col]);
                if (s == 0)      cur[tn][q] = t;
                else if (s == 1) cur[tn][q] = t + us2f(Hw[lhi * 4 + q][col]);
                else if (s == 2) { cur[tn][q] = t + X[(size_t)grow * HD + col]; trunk[tn][q] = cur[tn][q]; }
                else if (s == 3 || s == 5) cur[tn][q] = t;
                else { cur[tn][q] = t + trunk[tn][q]; trunk[tn][q] = cur[tn][q]; }
            }
        }
    }
    #pragma unroll
    for (int tn = 0; tn < 8; ++tn) {
        int col = tn * 16 + llo;
        #pragma unroll
        for (int q = 0; q < 4; ++q) {
            int grow = row0 + lhi * 4 + q;
            if (grow >= c1) continue;
            size_t o = (size_t)grow * HD + col;
            X[o] = cur[tn][q];
            Xbo[o] = f2us(cur[tn][q]);
        }
    }
}

// ---------------------------------------------------------------------------
// Atom-side: wide CSR gather + small chain (Wl in fragment order)
// ---------------------------------------------------------------------------
__global__ __launch_bounds__(256)
void gatherT_k(const ushort_t* __restrict__ Xb, const float* __restrict__ rbf,
               const float* __restrict__ Wr6, const int* __restrict__ eoffs,
               const int* __restrict__ esorted, ushort_t* __restrict__ TA, int M)
{
    __shared__ float W6s[NRR * HD];
    const int tid = threadIdx.x, wave = tid >> 6, lane = tid & 63;
    for (int i = tid; i < NRR * HD; i += 256) W6s[i] = Wr6[i];
    __syncthreads();
    int a0 = (blockIdx.x * 4 + wave) * 2;
    #pragma unroll
    for (int s = 0; s < 2; ++s) {
        int a = a0 + s;
        if (a >= M) return;
        float acc0 = 0.f, acc1 = 0.f;
        int k1 = eoffs[a + 1];
        for (int k = eoffs[a]; k < k1; ++k) {
            int e = esorted[k];
            float r6[NRR];
            #pragma unroll
            for (int r = 0; r < NRR; ++r) r6[r] = rbf[(size_t)e * NRR + r];
            float rp0 = 0.f, rp1 = 0.f;
            #pragma unroll
            for (int r = 0; r < NRR; ++r) {
                rp0 += r6[r] * W6s[r * HD + lane];
                rp1 += r6[r] * W6s[r * HD + 64 + lane];
            }
            acc0 += rp0 * us2f(Xb[(size_t)e * HD + lane]);
            acc1 += rp1 * us2f(Xb[(size_t)e * HD + 64 + lane]);
        }
        TA[(size_t)a * HD + lane] = f2us(acc0);
        TA[(size_t)a * HD + 64 + lane] = f2us(acc1);
    }
}

__global__ __launch_bounds__(256, 3)
void atomchain_w(const ushort_t* __restrict__ TA, const ushort_t* __restrict__ Wl,
                 const float* __restrict__ bl, const float* __restrict__ wout,
                 float* __restrict__ P, int M)
{
    __shared__ float blS[3 * HD];
    __shared__ float woS[HD];
    __shared__ ushort_t T[4][16][136];
    const int tid = threadIdx.x, wave = tid >> 6, lane = tid & 63;
    const int llo = lane & 15, lhi = lane >> 4;
    for (int i = tid; i < 3 * HD; i += 256) blS[i] = bl[i];
    if (tid < HD) woS[tid] = wout[tid];
    __syncthreads();
    const int row0 = (blockIdx.x * 4 + wave) * 16;
    if (row0 >= M) return;
    ushort_t (*Tw)[136] = T[wave];

    #pragma unroll
    for (int s = 0; s < 3; ++s) {
        short8 af[4];
        if (s == 0) {
            #pragma unroll
            for (int kc = 0; kc < 4; ++kc)
                af[kc] = *(const short8*)(TA + (size_t)(row0 + llo) * HD + kc * 32 + lhi * 8);
        } else {
            #pragma unroll
            for (int kc = 0; kc < 4; ++kc)
                af[kc] = *(const short8*)&Tw[llo][kc * 32 + lhi * 8];
        }
        const ushort_t* W = Wl + (size_t)s * MSZ;
        floatx4 acc[8]; ZERO_ACC8(acc);
        #pragma unroll
        for (int kc = 0; kc < 4; ++kc) {
            short8 bq[8];
            #pragma unroll
            for (int tn = 0; tn < 8; ++tn) bq[tn] = ldfrag(W, kc * 8 + tn, lane);
            #pragma unroll
            for (int tn = 0; tn < 8; ++tn)
                acc[tn] = __builtin_amdgcn_mfma_f32_16x16x32_bf16(af[kc], bq[tn], acc[tn], 0, 0, 0);
        }
        if (s < 2) {
            wave_lds_fence();
            #pragma unroll
            for (int tn = 0; tn < 8; ++tn) {
                int col = tn * 16 + llo;
                #pragma unroll
                for (int q = 0; q < 4; ++q)
                    Tw[lhi * 4 + q][col] = f2us(siluf(acc[tn][q] + blS[s * HD + col]));
            }
            wave_lds_fence();
        } else {
            #pragma unroll
            for (int q = 0; q < 4; ++q) {
                float v = 0.f;
                #pragma unroll
                for (int tn = 0; tn < 8; ++tn) {
                    int col = tn * 16 + llo;
                    v += siluf(acc[tn][q] + blS[2 * HD + col]) * woS[col];
                }
                v += __shfl_xor(v, 1); v += __shfl_xor(v, 2);
                v += __shfl_xor(v, 4); v += __shfl_xor(v, 8);
                int a = row0 + lhi * 4 + q;
                if (llo == 0 && a < M) P[a] += v;
            }
        }
    }
}

// ---------------- small kernels ----------------
__global__ void emb_lin_k(const float* __restrict__ emb_table, const float* __restrict__ emb_w,
                          float* __restrict__ A0, float* __restrict__ A1)
{
    __shared__ float er[HD];
    int a = blockIdx.x, h = threadIdx.x;
    er[h] = emb_table[a * HD + h];
    __syncthreads();
    float acc0 = 0.f, acc1 = 0.f;
    #pragma unroll 8
    for (int l = 0; l < HD; ++l) {
        float e = er[l];
        acc0 += e * emb_w[l * HD + h];
        acc1 += e * emb_w[(HD + l) * HD + h];
    }
    A0[a * HD + h] = acc0;
    A1[a * HD + h] = acc1;
}

__global__ void sbf_proj_s(const float* __restrict__ sbf, const float* __restrict__ W,
                           const int* __restrict__ tpos, ushort_t* __restrict__ sps)
{
    __shared__ float Ws[NSNR * NBB];
    for (int s = threadIdx.x; s < NSNR * NBB; s += 256) Ws[s] = W[s];
    __syncthreads();
    int t = blockIdx.x * 256 + threadIdx.x;
    if (t >= NTRIP) return;
    float acc[NBB];
    #pragma unroll
    for (int n = 0; n < NBB; ++n) acc[n] = 0.f;
    #pragma unroll
    for (int r = 0; r < NSNR; ++r) {
        float v = sbf[(size_t)t * NSNR + r];
        #pragma unroll
        for (int n = 0; n < NBB; ++n) acc[n] += v * Ws[r * NBB + n];
    }
    int p = tpos[t];
    ushort_t* o = sps + (size_t)p * NBB;
    #pragma unroll
    for (int n = 0; n < NBB; ++n) o[n] = f2us(acc[n]);
}

__global__ void graph_sum_k(const float* __restrict__ P, const int* __restrict__ batch,
                            float* __restrict__ outg)
{
    int a = blockIdx.x * 256 + threadIdx.x;
    if (a >= NATOMS) return;
    atomicAdd(&outg[batch[a]], P[a]);
}

// ---------------------------------------------------------------------------
extern "C" void kernel_launch(void* const* d_in, const int* in_sizes, int n_in,
                              void* d_out, int out_size, void* d_ws, size_t ws_size,
                              hipStream_t stream)
{
    const int*   z         = (const int*)  d_in[0];
    const float* rbf       = (const float*)d_in[1];
    const float* sbf       = (const float*)d_in[2];
    const int*   ii        = (const int*)  d_in[3];
    const int*   jj        = (const int*)  d_in[4];
    const int*   idx_kj    = (const int*)  d_in[5];
    const int*   idx_ji    = (const int*)  d_in[6];
    const int*   batch     = (const int*)  d_in[7];
    const float* emb_table = (const float*)d_in[8];
    const float* emb_rbf_w = (const float*)d_in[9];
    const float* emb_rbf_b = (const float*)d_in[10];
    const float* emb_w     = (const float*)d_in[11];
    const float* emb_b     = (const float*)d_in[12];
    const float* int_rbf_w = (const float*)d_in[13];
    const float* int_sbf_w = (const float*)d_in[14];
    const float* int_kj_w  = (const float*)d_in[15];
    const float* int_kj_b  = (const float*)d_in[16];
    const float* int_ji_w  = (const float*)d_in[17];
    const float* int_ji_b  = (const float*)d_in[18];
    const float* int_W     = (const float*)d_in[19];
    const float* int_bef_w = (const float*)d_in[20];
    const float* int_bef_b = (const float*)d_in[21];
    const float* int_lin_w = (const float*)d_in[22];
    const float* int_lin_b = (const float*)d_in[23];
    const float* int_aft_w = (const float*)d_in[24];
    const float* int_aft_b = (const float*)d_in[25];
    const float* out_rbf_w = (const float*)d_in[26];
    const float* out_lins_w= (const float*)d_in[27];
    const float* out_lins_b= (const float*)d_in[28];
    const float* out_w     = (const float*)d_in[29];
    float* d_outf          = (float*)d_out;

    const size_t EH = (size_t)NEDGES * HD;
    const int OFF_EMB = 0, OFF_KJ = 1, OFF_JI = 7, OFF_CHAIN = 13, OFF_OUTL = 55;

    char* base = (char*)d_ws;
    auto take = [&](size_t bytes) { char* p = base; base += (bytes + 255) & ~(size_t)255; return p; };
    float* bufA    = (float*)take(EH * 4);
    ushort_t* Xb   = (ushort_t*)take(EH * 2);
    ushort_t* Cb   = (ushort_t*)take(EH * 2);
    ushort_t* sps  = (ushort_t*)take((size_t)NTRIP * NBB * 2);
    ushort_t* TA   = (ushort_t*)take((size_t)NATOMS * HD * 2);
    float* P_atom  = (float*)take((size_t)NATOMS * 4);
    float* A0      = (float*)take(95 * HD * 4);
    float* A1      = (float*)take(95 * HD * 4);
    float* bc      = (float*)take((size_t)NBLKS * 7 * HD * 4);
    int*   counts  = (int*)  take((size_t)(NEDGES + 1) * 4);
    int*   bsum    = (int*)  take(1024 * 4);
    int*   toffs   = (int*)  take((size_t)(NEDGES + 1) * 4);
    int*   eoffs   = (int*)  take((size_t)(NATOMS + 1) * 4);
    int*   tsorted = (int*)  take((size_t)NTRIP * 4);
    int*   esorted = (int*)  take((size_t)NEDGES * 4);
    int*   tpos    = (int*)  take((size_t)NTRIP * 4);
    int*   ekjs    = (int*)  take((size_t)NTRIP * 4);
    ushort_t* w128 = (ushort_t*)take((size_t)76 * MSZ * 2);
    ushort_t* wM   = (ushort_t*)take((size_t)NBLKS * HD * 1024 * 2);
    size_t fixed   = (size_t)(base - (char*)d_ws);
    ushort_t* G    = (ushort_t*)base;

    // G chunking: at least 4 chunks (keep each chunk L3-resident)
    int nch = 8;
    for (int c = 4; c <= 8; ++c) {
        int ch = ((NEDGES + c - 1) / c + 15) & ~15;
        size_t gb = (size_t)ch * 1024 * 2;
        if (fixed + gb <= ws_size) { nch = c; break; }
    }
    const int CH = ((NEDGES + nch - 1) / nch + 15) & ~15;

    auto zero = [&](float* p, size_t n) {
        zerof_k<<<((int)n + 255) / 256, 256, 0, stream>>>(p, (int)n);
    };

    // ---------------- weight prep ----------------
    transp128_k<<< 1, 256, 0, stream>>>(emb_w + 2 * MSZ, w128 + (size_t)OFF_EMB * MSZ);
    transp128s_k<<< 6, 256, 0, stream>>>(int_kj_w,   w128 + (size_t)OFF_KJ  * MSZ);
    transp128s_k<<< 6, 256, 0, stream>>>(int_ji_w,   w128 + (size_t)OFF_JI  * MSZ);
    for (int b = 0; b < NBLKS; ++b) {
        transp128s_k<<<2, 256, 0, stream>>>(int_bef_w + (size_t)b * 2 * MSZ,
                                            w128 + (size_t)(OFF_CHAIN + b * 7) * MSZ);
        transp128s_k<<<1, 256, 0, stream>>>(int_lin_w + (size_t)b * MSZ,
                                            w128 + (size_t)(OFF_CHAIN + b * 7 + 2) * MSZ);
        transp128s_k<<<4, 256, 0, stream>>>(int_aft_w + (size_t)b * 4 * MSZ,
                                            w128 + (size_t)(OFF_CHAIN + b * 7 + 3) * MSZ);
    }
    transp128s_k<<<21, 256, 0, stream>>>(out_lins_w, w128 + (size_t)OFF_OUTL * MSZ);
    castWMs_k<<<(NBLKS * HD * 1024 + 255) / 256, 256, 0, stream>>>(int_W, wM, NBLKS * HD * 1024);
    pack_bc_k<<<NBLKS, 256, 0, stream>>>(int_bef_b, int_lin_b, int_aft_b, bc);

    // ---------------- CSR builds ----------------
    {
        zeroi_k<<<(NEDGES + 255) / 256, 256, 0, stream>>>(counts, NEDGES);
        hist_k<<<(NTRIP + 255) / 256, 256, 0, stream>>>(idx_ji, NTRIP, counts);
        int nb = (NEDGES + 255) / 256;
        blksum_k<<<nb, 256, 0, stream>>>(counts, NEDGES, bsum);
        scanb_k<<<1, 1024, 0, stream>>>(bsum, nb);
        scanfin_k<<<nb, 256, 0, stream>>>(counts, NEDGES, bsum, toffs);
        zeroi_k<<<(NEDGES + 255) / 256, 256, 0, stream>>>(counts, NEDGES);
        fill_k<<<(NTRIP + 255) / 256, 256, 0, stream>>>(idx_ji, NTRIP, toffs, counts, tsorted);
        invperm_k<<<(NTRIP + 255) / 256, 256, 0, stream>>>(tsorted, idx_kj, tpos, ekjs, NTRIP);
    }
    {
        zeroi_k<<<(NATOMS + 255) / 256, 256, 0, stream>>>(counts, NATOMS);
        hist_k<<<(NEDGES + 255) / 256, 256, 0, stream>>>(ii, NEDGES, counts);
        int nb = (NATOMS + 255) / 256;
        blksum_k<<<nb, 256, 0, stream>>>(counts, NATOMS, bsum);
        scanb_k<<<1, 1024, 0, stream>>>(bsum, nb);
        scanfin_k<<<nb, 256, 0, stream>>>(counts, NATOMS, bsum, eoffs);
        zeroi_k<<<(NATOMS + 255) / 256, 256, 0, stream>>>(counts, NATOMS);
        fill_k<<<(NEDGES + 255) / 256, 256, 0, stream>>>(ii, NEDGES, eoffs, counts, esorted);
    }

    const int EGRID = (NEDGES + 127) / 128;
    const int EW    = (NEDGES / 16 + 3) / 4;
    const int AW    = (NATOMS / 16 + 3) / 4;
    const int GW    = (NATOMS / 2 + 3) / 4;
    auto out_block = [&](int k) {
        gatherT_k<<<GW, 256, 0, stream>>>(
            Xb, rbf, out_rbf_w + (size_t)k * NRR * HD, eoffs, esorted, TA, NATOMS);
        atomchain_w<<<AW, 256, 0, stream>>>(
            TA, w128 + (size_t)(OFF_OUTL + 3 * k) * MSZ,
            out_lins_b + (size_t)k * 3 * HD, out_w + (size_t)k * HD, P_atom, NATOMS);
    };

    // ---------------- Embedding ----------------
    emb_lin_k<<<95, HD, 0, stream>>>(emb_table, emb_w, A0, A1);
    emb_chain_k<<<EGRID, 256, 0, stream>>>(
        rbf, emb_rbf_w, emb_rbf_b, w128 + (size_t)OFF_EMB * MSZ,
        A0, A1, emb_b, z, ii, jj, bufA, Xb, NEDGES);

    zero(P_atom, NATOMS);
    out_block(0);

    // ---------------- Interaction blocks ----------------
    for (int b = 0; b < NBLKS; ++b) {
        sbf_proj_s<<<(NTRIP + 255) / 256, 256, 0, stream>>>(
            sbf, int_sbf_w + (size_t)b * NSNR * NBB, tpos, sps);

        kjcb_w<<<EW, 256, 0, stream>>>(
            Xb, w128 + (size_t)(OFF_KJ + b) * MSZ, int_kj_b + (size_t)b * HD,
            rbf, int_rbf_w + (size_t)b * NRR * HD, Cb, NEDGES);

        for (int c = 0; c < nch; ++c) {
            int c0 = c * CH;
            int c1 = (c0 + CH < NEDGES) ? c0 + CH : NEDGES;
            if (c0 >= c1) break;
            int ne = c1 - c0;
            trip_accum_k<<<(ne + 1) / 2, 256, 0, stream>>>(
                sps, Cb, toffs, ekjs, G, c0, c1);
            int gw = ((ne + 15) / 16 + 3) / 4;
            megaK_w<<<gw, 256, 0, stream>>>(
                G, Xb, wM + (size_t)b * HD * 1024,
                w128 + (size_t)(OFF_JI + b) * MSZ, int_ji_b + (size_t)b * HD,
                w128 + (size_t)(OFF_CHAIN + b * 7) * MSZ, bc + (size_t)b * 7 * HD,
                bufA, Xb, c0, c1);
        }

        out_block(b + 1);
    }

    // ---------------- Final graph reduction ----------------
    zero(d_outf, NGRAPH);
    graph_sum_k<<<(NATOMS + 255) / 256, 256, 0, stream>>>(P_atom, batch, d_outf);
}